// Round 4
// baseline (175.753 us; speedup 1.0000x reference)
//
#include <hip/hip_runtime.h>
#include <hip/hip_bf16.h>

// Problem constants
#define B_  8
#define L_  1024
#define D_  1024
#define N_  16
#define R_  64
#define NC_ 1000

#define XP_KS   8             // xproj split-K factor
#define XP_TM   64            // xproj rows per block
#define XP_KC   (D_ / XP_KS)  // 128 K per block
#define XP_M    (B_ * L_)     // 8192

#define HB_  4                // batches per half
#define CH8  8                // scan chunks over L
#define TCH8 (L_ / CH8)       // 128 timesteps per chunk
#define TB   64               // LDS staging batch (timesteps)

// ---------------------------------------------------------------------------
// Kernel 1a: partial xproj. part[ks][m][96] = sum_{k in slice ks} x[m][k]*W[c][k]
// Grid (128, 8) = 1024 blocks. W staged transposed (wt[kk][col], pad 100):
// compute reads are 3x ds_read_b128 over cols 12*tx -> conflict-free.
// ---------------------------------------------------------------------------
__global__ __launch_bounds__(256) void xproj_kernel(
    const float* __restrict__ x, const float* __restrict__ W,
    float* __restrict__ part) {
  __shared__ float xs[XP_TM][36];
  __shared__ float wt[32][100];
  const int tid = threadIdx.x;
  const int tx = tid & 7;
  const int ty = tid >> 3;
  const int m0 = blockIdx.x * XP_TM;
  const int ks = blockIdx.y;

  float acc[2][12];
#pragma unroll
  for (int r = 0; r < 2; ++r)
#pragma unroll
    for (int j = 0; j < 12; ++j) acc[r][j] = 0.f;

  for (int step = 0; step < XP_KC / 32; ++step) {
    const int kbase = ks * XP_KC + step * 32;
    __syncthreads();
#pragma unroll
    for (int j = 0; j < 2; ++j) {
      const int f4 = tid + j * 256;
      const int row = f4 >> 3, c4 = f4 & 7;
      float4 v = *(const float4*)(x + (size_t)(m0 + row) * D_ + kbase + c4 * 4);
      *(float4*)(&xs[row][c4 * 4]) = v;
    }
#pragma unroll
    for (int j = 0; j < 3; ++j) {
      const int idx = tid + j * 256;
      const int wr = idx >> 3, c4 = idx & 7;
      float4 v = *(const float4*)(W + (size_t)wr * D_ + kbase + c4 * 4);
      wt[c4 * 4 + 0][wr] = v.x;
      wt[c4 * 4 + 1][wr] = v.y;
      wt[c4 * 4 + 2][wr] = v.z;
      wt[c4 * 4 + 3][wr] = v.w;
    }
    __syncthreads();
#pragma unroll 4
    for (int kk = 0; kk < 32; ++kk) {
      const float a0 = xs[ty * 2 + 0][kk];
      const float a1 = xs[ty * 2 + 1][kk];
      const float4 b0 = *(const float4*)(&wt[kk][tx * 12 + 0]);
      const float4 b1 = *(const float4*)(&wt[kk][tx * 12 + 4]);
      const float4 b2 = *(const float4*)(&wt[kk][tx * 12 + 8]);
      acc[0][0] = fmaf(a0, b0.x, acc[0][0]);
      acc[0][1] = fmaf(a0, b0.y, acc[0][1]);
      acc[0][2] = fmaf(a0, b0.z, acc[0][2]);
      acc[0][3] = fmaf(a0, b0.w, acc[0][3]);
      acc[0][4] = fmaf(a0, b1.x, acc[0][4]);
      acc[0][5] = fmaf(a0, b1.y, acc[0][5]);
      acc[0][6] = fmaf(a0, b1.z, acc[0][6]);
      acc[0][7] = fmaf(a0, b1.w, acc[0][7]);
      acc[0][8] = fmaf(a0, b2.x, acc[0][8]);
      acc[0][9] = fmaf(a0, b2.y, acc[0][9]);
      acc[0][10] = fmaf(a0, b2.z, acc[0][10]);
      acc[0][11] = fmaf(a0, b2.w, acc[0][11]);
      acc[1][0] = fmaf(a1, b0.x, acc[1][0]);
      acc[1][1] = fmaf(a1, b0.y, acc[1][1]);
      acc[1][2] = fmaf(a1, b0.z, acc[1][2]);
      acc[1][3] = fmaf(a1, b0.w, acc[1][3]);
      acc[1][4] = fmaf(a1, b1.x, acc[1][4]);
      acc[1][5] = fmaf(a1, b1.y, acc[1][5]);
      acc[1][6] = fmaf(a1, b1.z, acc[1][6]);
      acc[1][7] = fmaf(a1, b1.w, acc[1][7]);
      acc[1][8] = fmaf(a1, b2.x, acc[1][8]);
      acc[1][9] = fmaf(a1, b2.y, acc[1][9]);
      acc[1][10] = fmaf(a1, b2.z, acc[1][10]);
      acc[1][11] = fmaf(a1, b2.w, acc[1][11]);
    }
  }
#pragma unroll
  for (int r = 0; r < 2; ++r) {
    float* p = part + ((size_t)ks * XP_M + m0 + ty * 2 + r) * 96 + tx * 12;
    *(float4*)(p + 0) = make_float4(acc[r][0], acc[r][1], acc[r][2], acc[r][3]);
    *(float4*)(p + 4) = make_float4(acc[r][4], acc[r][5], acc[r][6], acc[r][7]);
    *(float4*)(p + 8) = make_float4(acc[r][8], acc[r][9], acc[r][10], acc[r][11]);
  }
}

// ---------------------------------------------------------------------------
// Kernel 1b: reduce 8 K-slice partials -> xdb[m][96].
// ---------------------------------------------------------------------------
__global__ __launch_bounds__(256) void xreduce_kernel(
    const float* __restrict__ part, float* __restrict__ xdb) {
  const size_t gidx = (size_t)blockIdx.x * 256 + threadIdx.x;
  const float4* p4 = (const float4*)part;
  const size_t stride = (size_t)XP_M * 96 / 4;
  float4 s = p4[gidx];
#pragma unroll
  for (int ks = 1; ks < XP_KS; ++ks) {
    const float4 v = p4[(size_t)ks * stride + gidx];
    s.x += v.x; s.y += v.y; s.z += v.z; s.w += v.w;
  }
  ((float4*)xdb)[gidx] = s;
}

// ---------------------------------------------------------------------------
// Kernel 2: dt for one half-batch (4096 rows). xdbh = xdb offset to the half.
// dtbH[mloc][d] = softplus(sum_r xdbh[mloc][r]*W_dt[d][r] + b_dt[d])
// ---------------------------------------------------------------------------
__global__ __launch_bounds__(256) void dt_kernel(
    const float* __restrict__ xdbh, const float* __restrict__ W_dt,
    const float* __restrict__ b_dt, float* __restrict__ dtbH) {
  __shared__ float dtr[32][64];
  const int tid = threadIdx.x;
  const int d = blockIdx.y * 256 + tid;
  const int m0 = blockIdx.x * 32;

  float4 w[16];
#pragma unroll
  for (int i = 0; i < 16; ++i)
    w[i] = *(const float4*)(W_dt + (size_t)d * R_ + i * 4);
  const float bd = b_dt[d];

#pragma unroll
  for (int j = 0; j < 2; ++j) {
    const int f4 = tid + j * 256;
    const int row = f4 >> 4, c4 = f4 & 15;
    float4 v = *(const float4*)(xdbh + (size_t)(m0 + row) * 96 + c4 * 4);
    *(float4*)(&dtr[row][c4 * 4]) = v;
  }
  __syncthreads();

#pragma unroll 4
  for (int row = 0; row < 32; ++row) {
    float a0 = 0.f, a1 = 0.f, a2 = 0.f, a3 = 0.f;
#pragma unroll
    for (int rc = 0; rc < 16; ++rc) {
      const float4 v = *(const float4*)(&dtr[row][rc * 4]);
      a0 = fmaf(v.x, w[rc].x, a0);
      a1 = fmaf(v.y, w[rc].y, a1);
      a2 = fmaf(v.z, w[rc].z, a2);
      a3 = fmaf(v.w, w[rc].w, a3);
    }
    const float s = bd + ((a0 + a1) + (a2 + a3));
    const float sp = fmaxf(s, 0.f) + log1pf(__expf(-fabsf(s)));
    dtbH[(size_t)(m0 + row) * D_ + d] = sp;
  }
}

// ---------------------------------------------------------------------------
// Kernel 3: LDS-staged chunked scan for one half-batch.
// Block: 256 = 16 d x 16 n. Grid: (HB_*64 dtiles, CH8 chunks) = 2048 blocks
// -> 8 blocks/CU = 32 waves/CU. Stages x/dt [64][16] tiles (one 64B line per
// row, float4-coalesced) and B/C [64][32]; inner reads are LDS broadcasts.
// Writes per-chunk (cumP, S1, S2, hend) float4 + xsum for exact combine.
// ---------------------------------------------------------------------------
__global__ __launch_bounds__(256) void scan_kernel(
    const float* __restrict__ x, const float* __restrict__ xdb,
    const float* __restrict__ dtbH, const float* __restrict__ A_log,
    float* __restrict__ summ, float* __restrict__ sumx, int half) {
  __shared__ float xs[TB][16];
  __shared__ float dts[TB][16];
  __shared__ float bcs[TB][32];
  const int tid = threadIdx.x;
  const int n = tid & 15;
  const int dl = tid >> 4;         // 0..15
  const int bh = blockIdx.x >> 6;  // 0..3
  const int dtile = blockIdx.x & 63;
  const int c = blockIdx.y;        // 0..7
  const int d0 = dtile * 16;
  const int d = d0 + dl;
  const int bg = half * HB_ + bh;

  const float Aval = -__expf(A_log[(size_t)d * N_ + n]);

  const int t0 = c * TCH8;
  float cumP = 1.f, loc = 0.f, S1 = 0.f, S2 = 0.f, xsum = 0.f;

  // staging indices (constant per thread)
  const int srow = tid >> 2, sc4 = (tid & 3) * 4;   // x/dt tiles
  const int brow = tid >> 3, bc4 = (tid & 7) * 4;   // bc tile

  for (int tb = 0; tb < TCH8; tb += TB) {
    const int tbase = t0 + tb;
    __syncthreads();
    {
      const size_t gx = ((size_t)bg * L_ + tbase + srow) * D_ + d0 + sc4;
      *(float4*)(&xs[srow][sc4]) = *(const float4*)(x + gx);
      const size_t gd = ((size_t)bh * L_ + tbase + srow) * D_ + d0 + sc4;
      *(float4*)(&dts[srow][sc4]) = *(const float4*)(dtbH + gd);
      const size_t gb = ((size_t)bg * L_ + tbase + brow) * 96 + 64 + bc4;
      *(float4*)(&bcs[brow][bc4]) = *(const float4*)(xdb + gb);
      const size_t gb2 = ((size_t)bg * L_ + tbase + 32 + brow) * 96 + 64 + bc4;
      *(float4*)(&bcs[32 + brow][bc4]) = *(const float4*)(xdb + gb2);
    }
    __syncthreads();
#pragma unroll 8
    for (int tt = 0; tt < TB; ++tt) {
      const float xv = xs[tt][dl];
      const float dtv = dts[tt][dl];
      const float Bv = bcs[tt][n];
      const float Cv = bcs[tt][16 + n];
      const float dA = __expf(dtv * Aval);
      cumP *= dA;
      loc = fmaf(dA, loc, dtv * Bv * xv);
      S1 = fmaf(cumP, Cv, S1);
      S2 = fmaf(loc, Cv, S2);
      xsum += xv;
    }
  }
  const size_t si = (((size_t)c * HB_ + bh) * D_ + d) * N_ + n;
  ((float4*)summ)[si] = make_float4(cumP, S1, S2, loc);
  if (n == 0) sumx[((size_t)c * HB_ + bh) * D_ + d] = xsum;
}

// ---------------------------------------------------------------------------
// Kernel 3b: exact sequential chunk combine + n-reduce -> pooled (one half).
// ---------------------------------------------------------------------------
__global__ __launch_bounds__(256) void combine_kernel(
    const float* __restrict__ summ, const float* __restrict__ sumx,
    const float* __restrict__ D_param, float* __restrict__ pooled, int half) {
  const int gid = blockIdx.x * 256 + threadIdx.x;  // 0..65535
  const int n = gid & 15;
  const int d = (gid >> 4) & (D_ - 1);
  const int bh = gid >> 14;  // 0..3
  float hin = 0.f, acc = 0.f;
  const float4* s4 = (const float4*)summ;
#pragma unroll
  for (int c = 0; c < CH8; ++c) {
    const float4 f = s4[(((size_t)c * HB_ + bh) * D_ + d) * N_ + n];
    acc = fmaf(hin, f.y, acc) + f.z;
    hin = fmaf(f.x, hin, f.w);
  }
  acc += __shfl_xor(acc, 1);
  acc += __shfl_xor(acc, 2);
  acc += __shfl_xor(acc, 4);
  acc += __shfl_xor(acc, 8);
  if (n == 0) {
    float xst = 0.f;
#pragma unroll
    for (int c = 0; c < CH8; ++c)
      xst += sumx[((size_t)c * HB_ + bh) * D_ + d];
    const int bg = half * HB_ + bh;
    pooled[(size_t)bg * D_ + d] =
        (acc + D_param[d] * xst) * (1.0f / (float)L_);
  }
}

// ---------------------------------------------------------------------------
// Kernel 4: logits. One wave per class; all 8 batches from LDS-staged pooled.
// W_cls read exactly once (4 MB total, was ~8x that).
// ---------------------------------------------------------------------------
__global__ __launch_bounds__(256) void cls_kernel(
    const float* __restrict__ pooled, const float* __restrict__ W_cls,
    const float* __restrict__ b_cls, float* __restrict__ out) {
  __shared__ float pool[B_ * D_];  // 32 KB
  const int tid = threadIdx.x;
  const int c = blockIdx.x * 4 + (tid >> 6);
  const int lane = tid & 63;

#pragma unroll
  for (int j = 0; j < 8; ++j) {
    const int f4 = tid + j * 256;
    ((float4*)pool)[f4] = ((const float4*)pooled)[f4];
  }
  __syncthreads();

  float accb[B_];
#pragma unroll
  for (int b = 0; b < B_; ++b) accb[b] = 0.f;

#pragma unroll
  for (int i = 0; i < 4; ++i) {
    const float4 wv =
        *(const float4*)(W_cls + (size_t)c * D_ + i * 256 + lane * 4);
#pragma unroll
    for (int b = 0; b < B_; ++b) {
      const float4 p = *(const float4*)(&pool[b * D_ + i * 256 + lane * 4]);
      accb[b] = fmaf(wv.x, p.x,
                fmaf(wv.y, p.y, fmaf(wv.z, p.z, fmaf(wv.w, p.w, accb[b]))));
    }
  }
#pragma unroll
  for (int off = 1; off < 64; off <<= 1) {
#pragma unroll
    for (int b = 0; b < B_; ++b) accb[b] += __shfl_xor(accb[b], off);
  }
  if (lane < B_) out[(size_t)lane * NC_ + c] = accb[lane] + b_cls[c];
}

// ---------------------------------------------------------------------------
extern "C" void kernel_launch(void* const* d_in, const int* in_sizes, int n_in,
                              void* d_out, int out_size, void* d_ws,
                              size_t ws_size, hipStream_t stream) {
  const float* x = (const float*)d_in[0];
  const float* A_log = (const float*)d_in[1];
  const float* D_param = (const float*)d_in[2];
  const float* W_xproj = (const float*)d_in[3];
  const float* W_dt = (const float*)d_in[4];
  const float* b_dt = (const float*)d_in[5];
  const float* W_cls = (const float*)d_in[6];
  const float* b_cls = (const float*)d_in[7];
  float* out = (float*)d_out;

  // ws layout (28.5 MB total):
  //   xdb    [786432]                                (3 MB, live whole run)
  //   region [6332416] shared:
  //     part   = region            (6291456 fl)  dead after xreduce
  //     dtbH   = region            (4194304 fl)  per-half dt
  //     pooled = region + 4194304  (8192 fl)
  //     summ   = region + 4202496  (2097152 fl)  per-half chunk summaries
  //     sumx   = region + 6299648  (32768 fl)
  float* ws_f = (float*)d_ws;
  float* xdb = ws_f;
  float* region = ws_f + (size_t)XP_M * 96;
  float* part = region;
  float* dtbH = region;
  float* pooled = region + (size_t)HB_ * L_ * D_;
  float* summ = pooled + (size_t)B_ * D_;
  float* sumx = summ + (size_t)CH8 * HB_ * D_ * N_ * 4;

  xproj_kernel<<<dim3(XP_M / XP_TM, XP_KS), dim3(256), 0, stream>>>(
      x, W_xproj, part);
  xreduce_kernel<<<dim3(XP_M * 96 / 4 / 256), dim3(256), 0, stream>>>(part,
                                                                      xdb);
  for (int half = 0; half < 2; ++half) {
    const float* xdbh = xdb + (size_t)half * HB_ * L_ * 96;
    dt_kernel<<<dim3(HB_ * L_ / 32, 4), dim3(256), 0, stream>>>(xdbh, W_dt,
                                                                b_dt, dtbH);
    scan_kernel<<<dim3(HB_ * 64, CH8), dim3(256), 0, stream>>>(
        x, xdb, dtbH, A_log, summ, sumx, half);
    combine_kernel<<<dim3(HB_ * D_ * N_ / 256), dim3(256), 0, stream>>>(
        summ, sumx, D_param, pooled, half);
  }
  cls_kernel<<<dim3(NC_ / 4), dim3(256), 0, stream>>>(pooled, W_cls, b_cls,
                                                      out);
}

// Round 5
// 142.426 us; speedup vs baseline: 1.2340x; 1.2340x over previous
//
#include <hip/hip_runtime.h>
#include <hip/hip_bf16.h>

// Problem constants
#define B_  8
#define L_  1024
#define D_  1024
#define N_  16
#define R_  64
#define NC_ 1000

#define XP_KS   8             // xproj split-K factor
#define XP_TM   64            // xproj rows per block
#define XP_KC   (D_ / XP_KS)  // 128 K per block
#define XP_M    (B_ * L_)     // 8192

#define HB_  4                // batches per half
#define CH8  8                // scan chunks over L
#define TCH8 (L_ / CH8)       // 128 timesteps per chunk
#define TB   64               // LDS staging batch (timesteps)

// ---------------------------------------------------------------------------
// Kernel 1a: partial xproj. part[ks][m][96] = sum_{k in slice ks} x[m][k]*W[c][k]
// Grid (128, 8) = 1024 blocks. W staged transposed (wt[kk][col], pad 100):
// compute reads are 3x ds_read_b128 over cols 12*tx -> conflict-free.
// ---------------------------------------------------------------------------
__global__ __launch_bounds__(256) void xproj_kernel(
    const float* __restrict__ x, const float* __restrict__ W,
    float* __restrict__ part) {
  __shared__ float xs[XP_TM][36];
  __shared__ float wt[32][100];
  const int tid = threadIdx.x;
  const int tx = tid & 7;
  const int ty = tid >> 3;
  const int m0 = blockIdx.x * XP_TM;
  const int ks = blockIdx.y;

  float acc[2][12];
#pragma unroll
  for (int r = 0; r < 2; ++r)
#pragma unroll
    for (int j = 0; j < 12; ++j) acc[r][j] = 0.f;

  for (int step = 0; step < XP_KC / 32; ++step) {
    const int kbase = ks * XP_KC + step * 32;
    __syncthreads();
#pragma unroll
    for (int j = 0; j < 2; ++j) {
      const int f4 = tid + j * 256;
      const int row = f4 >> 3, c4 = f4 & 7;
      float4 v = *(const float4*)(x + (size_t)(m0 + row) * D_ + kbase + c4 * 4);
      *(float4*)(&xs[row][c4 * 4]) = v;
    }
#pragma unroll
    for (int j = 0; j < 3; ++j) {
      const int idx = tid + j * 256;
      const int wr = idx >> 3, c4 = idx & 7;
      float4 v = *(const float4*)(W + (size_t)wr * D_ + kbase + c4 * 4);
      wt[c4 * 4 + 0][wr] = v.x;
      wt[c4 * 4 + 1][wr] = v.y;
      wt[c4 * 4 + 2][wr] = v.z;
      wt[c4 * 4 + 3][wr] = v.w;
    }
    __syncthreads();
#pragma unroll 4
    for (int kk = 0; kk < 32; ++kk) {
      const float a0 = xs[ty * 2 + 0][kk];
      const float a1 = xs[ty * 2 + 1][kk];
      const float4 b0 = *(const float4*)(&wt[kk][tx * 12 + 0]);
      const float4 b1 = *(const float4*)(&wt[kk][tx * 12 + 4]);
      const float4 b2 = *(const float4*)(&wt[kk][tx * 12 + 8]);
      acc[0][0] = fmaf(a0, b0.x, acc[0][0]);
      acc[0][1] = fmaf(a0, b0.y, acc[0][1]);
      acc[0][2] = fmaf(a0, b0.z, acc[0][2]);
      acc[0][3] = fmaf(a0, b0.w, acc[0][3]);
      acc[0][4] = fmaf(a0, b1.x, acc[0][4]);
      acc[0][5] = fmaf(a0, b1.y, acc[0][5]);
      acc[0][6] = fmaf(a0, b1.z, acc[0][6]);
      acc[0][7] = fmaf(a0, b1.w, acc[0][7]);
      acc[0][8] = fmaf(a0, b2.x, acc[0][8]);
      acc[0][9] = fmaf(a0, b2.y, acc[0][9]);
      acc[0][10] = fmaf(a0, b2.z, acc[0][10]);
      acc[0][11] = fmaf(a0, b2.w, acc[0][11]);
      acc[1][0] = fmaf(a1, b0.x, acc[1][0]);
      acc[1][1] = fmaf(a1, b0.y, acc[1][1]);
      acc[1][2] = fmaf(a1, b0.z, acc[1][2]);
      acc[1][3] = fmaf(a1, b0.w, acc[1][3]);
      acc[1][4] = fmaf(a1, b1.x, acc[1][4]);
      acc[1][5] = fmaf(a1, b1.y, acc[1][5]);
      acc[1][6] = fmaf(a1, b1.z, acc[1][6]);
      acc[1][7] = fmaf(a1, b1.w, acc[1][7]);
      acc[1][8] = fmaf(a1, b2.x, acc[1][8]);
      acc[1][9] = fmaf(a1, b2.y, acc[1][9]);
      acc[1][10] = fmaf(a1, b2.z, acc[1][10]);
      acc[1][11] = fmaf(a1, b2.w, acc[1][11]);
    }
  }
#pragma unroll
  for (int r = 0; r < 2; ++r) {
    float* p = part + ((size_t)ks * XP_M + m0 + ty * 2 + r) * 96 + tx * 12;
    *(float4*)(p + 0) = make_float4(acc[r][0], acc[r][1], acc[r][2], acc[r][3]);
    *(float4*)(p + 4) = make_float4(acc[r][4], acc[r][5], acc[r][6], acc[r][7]);
    *(float4*)(p + 8) = make_float4(acc[r][8], acc[r][9], acc[r][10], acc[r][11]);
  }
}

// ---------------------------------------------------------------------------
// Kernel 1b: reduce 8 K-slice partials -> xdb[m][96].
// ---------------------------------------------------------------------------
__global__ __launch_bounds__(256) void xreduce_kernel(
    const float* __restrict__ part, float* __restrict__ xdb) {
  const size_t gidx = (size_t)blockIdx.x * 256 + threadIdx.x;
  const float4* p4 = (const float4*)part;
  const size_t stride = (size_t)XP_M * 96 / 4;
  float4 s = p4[gidx];
#pragma unroll
  for (int ks = 1; ks < XP_KS; ++ks) {
    const float4 v = p4[(size_t)ks * stride + gidx];
    s.x += v.x; s.y += v.y; s.z += v.z; s.w += v.w;
  }
  ((float4*)xdb)[gidx] = s;
}

// ---------------------------------------------------------------------------
// Kernel 2: dt for one half-batch (4096 rows).
// dtbH[mloc][d] = softplus(sum_r xdbh[mloc][r]*W_dt[d][r] + b_dt[d])
// m-tile 16 -> grid (256,4) = 1024 blocks = 4 blocks/CU (4 waves/SIMD).
// __launch_bounds__(256,4) caps VGPR at 128 so w[16] (64 VGPR) stays
// register-resident (round-4 had VGPR=48 -> W_dt re-fetched from L2 per row,
// latency-bound at 47 us). Softplus via __logf (log1pf is a ~30-instr libm
// polynomial; args are in (1,2] so __logf(1+u) is accurate to ~1e-7).
// ---------------------------------------------------------------------------
__global__ __launch_bounds__(256, 4) void dt_kernel(
    const float* __restrict__ xdbh, const float* __restrict__ W_dt,
    const float* __restrict__ b_dt, float* __restrict__ dtbH) {
  __shared__ float dtr[16][64];
  const int tid = threadIdx.x;
  const int d = blockIdx.y * 256 + tid;
  const int m0 = blockIdx.x * 16;

  float4 w[16];
#pragma unroll
  for (int i = 0; i < 16; ++i)
    w[i] = *(const float4*)(W_dt + (size_t)d * R_ + i * 4);
  const float bd = b_dt[d];

  {  // stage 16 rows x 64 floats of dt_r: 256 float4, one per thread
    const int row = tid >> 4, c4 = tid & 15;
    *(float4*)(&dtr[row][c4 * 4]) =
        *(const float4*)(xdbh + (size_t)(m0 + row) * 96 + c4 * 4);
  }
  __syncthreads();

#pragma unroll 4
  for (int row = 0; row < 16; ++row) {
    float a0 = 0.f, a1 = 0.f, a2 = 0.f, a3 = 0.f;
#pragma unroll
    for (int rc = 0; rc < 16; ++rc) {
      const float4 v = *(const float4*)(&dtr[row][rc * 4]);
      a0 = fmaf(v.x, w[rc].x, a0);
      a1 = fmaf(v.y, w[rc].y, a1);
      a2 = fmaf(v.z, w[rc].z, a2);
      a3 = fmaf(v.w, w[rc].w, a3);
    }
    const float s = bd + ((a0 + a1) + (a2 + a3));
    const float sp = fmaxf(s, 0.f) + __logf(1.0f + __expf(-fabsf(s)));
    dtbH[(size_t)(m0 + row) * D_ + d] = sp;
  }
}

// ---------------------------------------------------------------------------
// Kernel 3: LDS-staged chunked scan for one half-batch.
// Block: 256 = 16 d x 16 n. Grid: (HB_*64 dtiles, CH8 chunks) = 2048 blocks.
// ---------------------------------------------------------------------------
__global__ __launch_bounds__(256) void scan_kernel(
    const float* __restrict__ x, const float* __restrict__ xdb,
    const float* __restrict__ dtbH, const float* __restrict__ A_log,
    float* __restrict__ summ, float* __restrict__ sumx, int half) {
  __shared__ float xs[TB][16];
  __shared__ float dts[TB][16];
  __shared__ float bcs[TB][32];
  const int tid = threadIdx.x;
  const int n = tid & 15;
  const int dl = tid >> 4;         // 0..15
  const int bh = blockIdx.x >> 6;  // 0..3
  const int dtile = blockIdx.x & 63;
  const int c = blockIdx.y;        // 0..7
  const int d0 = dtile * 16;
  const int d = d0 + dl;
  const int bg = half * HB_ + bh;

  const float Aval = -__expf(A_log[(size_t)d * N_ + n]);

  const int t0 = c * TCH8;
  float cumP = 1.f, loc = 0.f, S1 = 0.f, S2 = 0.f, xsum = 0.f;

  const int srow = tid >> 2, sc4 = (tid & 3) * 4;   // x/dt tiles
  const int brow = tid >> 3, bc4 = (tid & 7) * 4;   // bc tile

  for (int tb = 0; tb < TCH8; tb += TB) {
    const int tbase = t0 + tb;
    __syncthreads();
    {
      const size_t gx = ((size_t)bg * L_ + tbase + srow) * D_ + d0 + sc4;
      *(float4*)(&xs[srow][sc4]) = *(const float4*)(x + gx);
      const size_t gd = ((size_t)bh * L_ + tbase + srow) * D_ + d0 + sc4;
      *(float4*)(&dts[srow][sc4]) = *(const float4*)(dtbH + gd);
      const size_t gb = ((size_t)bg * L_ + tbase + brow) * 96 + 64 + bc4;
      *(float4*)(&bcs[brow][bc4]) = *(const float4*)(xdb + gb);
      const size_t gb2 = ((size_t)bg * L_ + tbase + 32 + brow) * 96 + 64 + bc4;
      *(float4*)(&bcs[32 + brow][bc4]) = *(const float4*)(xdb + gb2);
    }
    __syncthreads();
#pragma unroll 8
    for (int tt = 0; tt < TB; ++tt) {
      const float xv = xs[tt][dl];
      const float dtv = dts[tt][dl];
      const float Bv = bcs[tt][n];
      const float Cv = bcs[tt][16 + n];
      const float dA = __expf(dtv * Aval);
      cumP *= dA;
      loc = fmaf(dA, loc, dtv * Bv * xv);
      S1 = fmaf(cumP, Cv, S1);
      S2 = fmaf(loc, Cv, S2);
      xsum += xv;
    }
  }
  const size_t si = (((size_t)c * HB_ + bh) * D_ + d) * N_ + n;
  ((float4*)summ)[si] = make_float4(cumP, S1, S2, loc);
  if (n == 0) sumx[((size_t)c * HB_ + bh) * D_ + d] = xsum;
}

// ---------------------------------------------------------------------------
// Kernel 3b: exact sequential chunk combine + n-reduce -> pooled (one half).
// ---------------------------------------------------------------------------
__global__ __launch_bounds__(256) void combine_kernel(
    const float* __restrict__ summ, const float* __restrict__ sumx,
    const float* __restrict__ D_param, float* __restrict__ pooled, int half) {
  const int gid = blockIdx.x * 256 + threadIdx.x;  // 0..65535
  const int n = gid & 15;
  const int d = (gid >> 4) & (D_ - 1);
  const int bh = gid >> 14;  // 0..3
  float hin = 0.f, acc = 0.f;
  const float4* s4 = (const float4*)summ;
#pragma unroll
  for (int c = 0; c < CH8; ++c) {
    const float4 f = s4[(((size_t)c * HB_ + bh) * D_ + d) * N_ + n];
    acc = fmaf(hin, f.y, acc) + f.z;
    hin = fmaf(f.x, hin, f.w);
  }
  acc += __shfl_xor(acc, 1);
  acc += __shfl_xor(acc, 2);
  acc += __shfl_xor(acc, 4);
  acc += __shfl_xor(acc, 8);
  if (n == 0) {
    float xst = 0.f;
#pragma unroll
    for (int c = 0; c < CH8; ++c)
      xst += sumx[((size_t)c * HB_ + bh) * D_ + d];
    const int bg = half * HB_ + bh;
    pooled[(size_t)bg * D_ + d] =
        (acc + D_param[d] * xst) * (1.0f / (float)L_);
  }
}

// ---------------------------------------------------------------------------
// Kernel 4: logits. One wave per class; all 8 batches from LDS-staged pooled.
// ---------------------------------------------------------------------------
__global__ __launch_bounds__(256) void cls_kernel(
    const float* __restrict__ pooled, const float* __restrict__ W_cls,
    const float* __restrict__ b_cls, float* __restrict__ out) {
  __shared__ float pool[B_ * D_];  // 32 KB
  const int tid = threadIdx.x;
  const int c = blockIdx.x * 4 + (tid >> 6);
  const int lane = tid & 63;

#pragma unroll
  for (int j = 0; j < 8; ++j) {
    const int f4 = tid + j * 256;
    ((float4*)pool)[f4] = ((const float4*)pooled)[f4];
  }
  __syncthreads();

  float accb[B_];
#pragma unroll
  for (int b = 0; b < B_; ++b) accb[b] = 0.f;

#pragma unroll
  for (int i = 0; i < 4; ++i) {
    const float4 wv =
        *(const float4*)(W_cls + (size_t)c * D_ + i * 256 + lane * 4);
#pragma unroll
    for (int b = 0; b < B_; ++b) {
      const float4 p = *(const float4*)(&pool[b * D_ + i * 256 + lane * 4]);
      accb[b] = fmaf(wv.x, p.x,
                fmaf(wv.y, p.y, fmaf(wv.z, p.z, fmaf(wv.w, p.w, accb[b]))));
    }
  }
#pragma unroll
  for (int off = 1; off < 64; off <<= 1) {
#pragma unroll
    for (int b = 0; b < B_; ++b) accb[b] += __shfl_xor(accb[b], off);
  }
  if (lane < B_) out[(size_t)lane * NC_ + c] = accb[lane] + b_cls[c];
}

// ---------------------------------------------------------------------------
extern "C" void kernel_launch(void* const* d_in, const int* in_sizes, int n_in,
                              void* d_out, int out_size, void* d_ws,
                              size_t ws_size, hipStream_t stream) {
  const float* x = (const float*)d_in[0];
  const float* A_log = (const float*)d_in[1];
  const float* D_param = (const float*)d_in[2];
  const float* W_xproj = (const float*)d_in[3];
  const float* W_dt = (const float*)d_in[4];
  const float* b_dt = (const float*)d_in[5];
  const float* W_cls = (const float*)d_in[6];
  const float* b_cls = (const float*)d_in[7];
  float* out = (float*)d_out;

  // ws layout (28.5 MB total): xdb | region{part | dtbH,pooled,summ,sumx}
  float* ws_f = (float*)d_ws;
  float* xdb = ws_f;
  float* region = ws_f + (size_t)XP_M * 96;
  float* part = region;
  float* dtbH = region;
  float* pooled = region + (size_t)HB_ * L_ * D_;
  float* summ = pooled + (size_t)B_ * D_;
  float* sumx = summ + (size_t)CH8 * HB_ * D_ * N_ * 4;

  xproj_kernel<<<dim3(XP_M / XP_TM, XP_KS), dim3(256), 0, stream>>>(
      x, W_xproj, part);
  xreduce_kernel<<<dim3(XP_M * 96 / 4 / 256), dim3(256), 0, stream>>>(part,
                                                                      xdb);
  for (int half = 0; half < 2; ++half) {
    const float* xdbh = xdb + (size_t)half * HB_ * L_ * 96;
    dt_kernel<<<dim3(HB_ * L_ / 16, 4), dim3(256), 0, stream>>>(xdbh, W_dt,
                                                                b_dt, dtbH);
    scan_kernel<<<dim3(HB_ * 64, CH8), dim3(256), 0, stream>>>(
        x, xdb, dtbH, A_log, summ, sumx, half);
    combine_kernel<<<dim3(HB_ * D_ * N_ / 256), dim3(256), 0, stream>>>(
        summ, sumx, D_param, pooled, half);
  }
  cls_kernel<<<dim3(NC_ / 4), dim3(256), 0, stream>>>(pooled, W_cls, b_cls,
                                                      out);
}

// Round 6
// 124.458 us; speedup vs baseline: 1.4121x; 1.1444x over previous
//
#include <hip/hip_runtime.h>
#include <hip/hip_bf16.h>

// Problem constants
#define B_  8
#define L_  1024
#define D_  1024
#define N_  16
#define R_  64
#define NC_ 1000

#define XP_KS   8             // xproj split-K factor
#define XP_TM   64            // xproj rows per block
#define XP_KC   (D_ / XP_KS)  // 128 K per block
#define XP_M    (B_ * L_)     // 8192

#define CH8  8                // scan chunks over L
#define TCH8 (L_ / CH8)       // 128 timesteps per chunk
#define TB   32               // LDS staging batch (timesteps)

// ---------------------------------------------------------------------------
// Kernel 1a: partial xproj. part[ks][m][96] = sum_{k in slice ks} x[m][k]*W[c][k]
// Grid (128, 8) = 1024 blocks. W staged transposed (wt[kk][col], pad 100):
// compute reads are 3x ds_read_b128 over cols 12*tx -> conflict-free.
// ---------------------------------------------------------------------------
__global__ __launch_bounds__(256) void xproj_kernel(
    const float* __restrict__ x, const float* __restrict__ W,
    float* __restrict__ part) {
  __shared__ float xs[XP_TM][36];
  __shared__ float wt[32][100];
  const int tid = threadIdx.x;
  const int tx = tid & 7;
  const int ty = tid >> 3;
  const int m0 = blockIdx.x * XP_TM;
  const int ks = blockIdx.y;

  float acc[2][12];
#pragma unroll
  for (int r = 0; r < 2; ++r)
#pragma unroll
    for (int j = 0; j < 12; ++j) acc[r][j] = 0.f;

  for (int step = 0; step < XP_KC / 32; ++step) {
    const int kbase = ks * XP_KC + step * 32;
    __syncthreads();
#pragma unroll
    for (int j = 0; j < 2; ++j) {
      const int f4 = tid + j * 256;
      const int row = f4 >> 3, c4 = f4 & 7;
      float4 v = *(const float4*)(x + (size_t)(m0 + row) * D_ + kbase + c4 * 4);
      *(float4*)(&xs[row][c4 * 4]) = v;
    }
#pragma unroll
    for (int j = 0; j < 3; ++j) {
      const int idx = tid + j * 256;
      const int wr = idx >> 3, c4 = idx & 7;
      float4 v = *(const float4*)(W + (size_t)wr * D_ + kbase + c4 * 4);
      wt[c4 * 4 + 0][wr] = v.x;
      wt[c4 * 4 + 1][wr] = v.y;
      wt[c4 * 4 + 2][wr] = v.z;
      wt[c4 * 4 + 3][wr] = v.w;
    }
    __syncthreads();
#pragma unroll 4
    for (int kk = 0; kk < 32; ++kk) {
      const float a0 = xs[ty * 2 + 0][kk];
      const float a1 = xs[ty * 2 + 1][kk];
      const float4 b0 = *(const float4*)(&wt[kk][tx * 12 + 0]);
      const float4 b1 = *(const float4*)(&wt[kk][tx * 12 + 4]);
      const float4 b2 = *(const float4*)(&wt[kk][tx * 12 + 8]);
      acc[0][0] = fmaf(a0, b0.x, acc[0][0]);
      acc[0][1] = fmaf(a0, b0.y, acc[0][1]);
      acc[0][2] = fmaf(a0, b0.z, acc[0][2]);
      acc[0][3] = fmaf(a0, b0.w, acc[0][3]);
      acc[0][4] = fmaf(a0, b1.x, acc[0][4]);
      acc[0][5] = fmaf(a0, b1.y, acc[0][5]);
      acc[0][6] = fmaf(a0, b1.z, acc[0][6]);
      acc[0][7] = fmaf(a0, b1.w, acc[0][7]);
      acc[0][8] = fmaf(a0, b2.x, acc[0][8]);
      acc[0][9] = fmaf(a0, b2.y, acc[0][9]);
      acc[0][10] = fmaf(a0, b2.z, acc[0][10]);
      acc[0][11] = fmaf(a0, b2.w, acc[0][11]);
      acc[1][0] = fmaf(a1, b0.x, acc[1][0]);
      acc[1][1] = fmaf(a1, b0.y, acc[1][1]);
      acc[1][2] = fmaf(a1, b0.z, acc[1][2]);
      acc[1][3] = fmaf(a1, b0.w, acc[1][3]);
      acc[1][4] = fmaf(a1, b1.x, acc[1][4]);
      acc[1][5] = fmaf(a1, b1.y, acc[1][5]);
      acc[1][6] = fmaf(a1, b1.z, acc[1][6]);
      acc[1][7] = fmaf(a1, b1.w, acc[1][7]);
      acc[1][8] = fmaf(a1, b2.x, acc[1][8]);
      acc[1][9] = fmaf(a1, b2.y, acc[1][9]);
      acc[1][10] = fmaf(a1, b2.z, acc[1][10]);
      acc[1][11] = fmaf(a1, b2.w, acc[1][11]);
    }
  }
#pragma unroll
  for (int r = 0; r < 2; ++r) {
    float* p = part + ((size_t)ks * XP_M + m0 + ty * 2 + r) * 96 + tx * 12;
    *(float4*)(p + 0) = make_float4(acc[r][0], acc[r][1], acc[r][2], acc[r][3]);
    *(float4*)(p + 4) = make_float4(acc[r][4], acc[r][5], acc[r][6], acc[r][7]);
    *(float4*)(p + 8) = make_float4(acc[r][8], acc[r][9], acc[r][10], acc[r][11]);
  }
}

// ---------------------------------------------------------------------------
// Kernel 1b: reduce 8 K-slice partials -> xdb[m][96].
// ---------------------------------------------------------------------------
__global__ __launch_bounds__(256) void xreduce_kernel(
    const float* __restrict__ part, float* __restrict__ xdb) {
  const size_t gidx = (size_t)blockIdx.x * 256 + threadIdx.x;
  const float4* p4 = (const float4*)part;
  const size_t stride = (size_t)XP_M * 96 / 4;
  float4 s = p4[gidx];
#pragma unroll
  for (int ks = 1; ks < XP_KS; ++ks) {
    const float4 v = p4[(size_t)ks * stride + gidx];
    s.x += v.x; s.y += v.y; s.z += v.z; s.w += v.w;
  }
  ((float4*)xdb)[gidx] = s;
}

// ---------------------------------------------------------------------------
// Kernel 2: dt (full batch). dtb[m][d] = softplus(dot(xdb[m][0:64], W_dt[d]) +
// b_dt[d]). m-tile 16, grid (512,4) = 2048 blocks. __launch_bounds__(256,4)
// keeps VGPR <= 128 so w[16] (64 VGPR) is register-resident.
// ---------------------------------------------------------------------------
__global__ __launch_bounds__(256, 4) void dt_kernel(
    const float* __restrict__ xdb, const float* __restrict__ W_dt,
    const float* __restrict__ b_dt, float* __restrict__ dtb) {
  __shared__ float dtr[16][64];
  const int tid = threadIdx.x;
  const int d = blockIdx.y * 256 + tid;
  const int m0 = blockIdx.x * 16;

  float4 w[16];
#pragma unroll
  for (int i = 0; i < 16; ++i)
    w[i] = *(const float4*)(W_dt + (size_t)d * R_ + i * 4);
  const float bd = b_dt[d];

  {  // stage 16 rows x 64 floats of dt_r: 256 float4, one per thread
    const int row = tid >> 4, c4 = tid & 15;
    *(float4*)(&dtr[row][c4 * 4]) =
        *(const float4*)(xdb + (size_t)(m0 + row) * 96 + c4 * 4);
  }
  __syncthreads();

#pragma unroll 4
  for (int row = 0; row < 16; ++row) {
    float a0 = 0.f, a1 = 0.f, a2 = 0.f, a3 = 0.f;
#pragma unroll
    for (int rc = 0; rc < 16; ++rc) {
      const float4 v = *(const float4*)(&dtr[row][rc * 4]);
      a0 = fmaf(v.x, w[rc].x, a0);
      a1 = fmaf(v.y, w[rc].y, a1);
      a2 = fmaf(v.z, w[rc].z, a2);
      a3 = fmaf(v.w, w[rc].w, a3);
    }
    const float s = bd + ((a0 + a1) + (a2 + a3));
    const float sp = fmaxf(s, 0.f) + __logf(1.0f + __expf(-fabsf(s)));
    dtb[(size_t)(m0 + row) * D_ + d] = sp;
  }
}

// ---------------------------------------------------------------------------
// Kernel 3: LDS-staged chunked scan, full batch, 2 d per thread.
// Block: 256 = 16 dl x 16 n, covering 32 d (dl and dl+16). Grid:
// (B*32 dtiles, CH8) = 2048 blocks -> 8 blocks/CU (12 KB LDS), 32 waves/CU.
// Per (d,n,t) unit: 3 LDS broadcast reads (was 4) since Bv/Cv are shared
// across the thread's two d. Writes per-chunk (cumP,S1,S2,hend)+xsum.
// ---------------------------------------------------------------------------
__global__ __launch_bounds__(256) void scan_kernel(
    const float* __restrict__ x, const float* __restrict__ xdb,
    const float* __restrict__ dtb, const float* __restrict__ A_log,
    float* __restrict__ summ, float* __restrict__ sumx) {
  __shared__ float xs[TB][32];
  __shared__ float dts[TB][32];
  __shared__ float bcs[TB][32];
  const int tid = threadIdx.x;
  const int n = tid & 15;
  const int dl = tid >> 4;          // 0..15
  const int b = blockIdx.x >> 5;    // 0..7
  const int dtile = blockIdx.x & 31;
  const int c = blockIdx.y;         // 0..7
  const int d0 = dtile * 32;
  const int da = d0 + dl, db = d0 + dl + 16;

  const float Av0 = -__expf(A_log[(size_t)da * N_ + n]);
  const float Av1 = -__expf(A_log[(size_t)db * N_ + n]);

  const int t0 = c * TCH8;
  float cumP0 = 1.f, loc0 = 0.f, S10 = 0.f, S20 = 0.f, xsum0 = 0.f;
  float cumP1 = 1.f, loc1 = 0.f, S11 = 0.f, S21 = 0.f, xsum1 = 0.f;

  const int srow = tid >> 3, sc4 = (tid & 7) * 4;  // 32 rows x 32 cols

  for (int tb = 0; tb < TCH8; tb += TB) {
    const int tbase = t0 + tb;
    __syncthreads();
    {
      const size_t gx = ((size_t)b * L_ + tbase + srow) * D_ + d0 + sc4;
      *(float4*)(&xs[srow][sc4]) = *(const float4*)(x + gx);
      *(float4*)(&dts[srow][sc4]) = *(const float4*)(dtb + gx);
      const size_t gb = ((size_t)b * L_ + tbase + srow) * 96 + 64 + sc4;
      *(float4*)(&bcs[srow][sc4]) = *(const float4*)(xdb + gb);
    }
    __syncthreads();
#pragma unroll 8
    for (int tt = 0; tt < TB; ++tt) {
      const float Bv = bcs[tt][n];
      const float Cv = bcs[tt][16 + n];
      const float xv0 = xs[tt][dl];
      const float xv1 = xs[tt][dl + 16];
      const float dtv0 = dts[tt][dl];
      const float dtv1 = dts[tt][dl + 16];
      const float e0 = __expf(dtv0 * Av0);
      cumP0 *= e0;
      loc0 = fmaf(e0, loc0, dtv0 * Bv * xv0);
      S10 = fmaf(cumP0, Cv, S10);
      S20 = fmaf(loc0, Cv, S20);
      xsum0 += xv0;
      const float e1 = __expf(dtv1 * Av1);
      cumP1 *= e1;
      loc1 = fmaf(e1, loc1, dtv1 * Bv * xv1);
      S11 = fmaf(cumP1, Cv, S11);
      S21 = fmaf(loc1, Cv, S21);
      xsum1 += xv1;
    }
  }
  const size_t si0 = (((size_t)c * B_ + b) * D_ + da) * N_ + n;
  const size_t si1 = (((size_t)c * B_ + b) * D_ + db) * N_ + n;
  ((float4*)summ)[si0] = make_float4(cumP0, S10, S20, loc0);
  ((float4*)summ)[si1] = make_float4(cumP1, S11, S21, loc1);
  if (n == 0) {
    sumx[((size_t)c * B_ + b) * D_ + da] = xsum0;
    sumx[((size_t)c * B_ + b) * D_ + db] = xsum1;
  }
}

// ---------------------------------------------------------------------------
// Kernel 3b: exact sequential chunk combine + n-reduce -> pooled (full batch).
// ---------------------------------------------------------------------------
__global__ __launch_bounds__(256) void combine_kernel(
    const float* __restrict__ summ, const float* __restrict__ sumx,
    const float* __restrict__ D_param, float* __restrict__ pooled) {
  const int gid = blockIdx.x * 256 + threadIdx.x;  // 0..131071
  const int n = gid & 15;
  const int d = (gid >> 4) & (D_ - 1);
  const int b = gid >> 14;  // 0..7
  float hin = 0.f, acc = 0.f;
  const float4* s4 = (const float4*)summ;
#pragma unroll
  for (int c = 0; c < CH8; ++c) {
    const float4 f = s4[(((size_t)c * B_ + b) * D_ + d) * N_ + n];
    acc = fmaf(hin, f.y, acc) + f.z;
    hin = fmaf(f.x, hin, f.w);
  }
  acc += __shfl_xor(acc, 1);
  acc += __shfl_xor(acc, 2);
  acc += __shfl_xor(acc, 4);
  acc += __shfl_xor(acc, 8);
  if (n == 0) {
    float xst = 0.f;
#pragma unroll
    for (int c = 0; c < CH8; ++c)
      xst += sumx[((size_t)c * B_ + b) * D_ + d];
    pooled[(size_t)b * D_ + d] =
        (acc + D_param[d] * xst) * (1.0f / (float)L_);
  }
}

// ---------------------------------------------------------------------------
// Kernel 4: logits. One wave per class; all 8 batches from LDS-staged pooled.
// ---------------------------------------------------------------------------
__global__ __launch_bounds__(256) void cls_kernel(
    const float* __restrict__ pooled, const float* __restrict__ W_cls,
    const float* __restrict__ b_cls, float* __restrict__ out) {
  __shared__ float pool[B_ * D_];  // 32 KB
  const int tid = threadIdx.x;
  const int c = blockIdx.x * 4 + (tid >> 6);
  const int lane = tid & 63;

#pragma unroll
  for (int j = 0; j < 8; ++j) {
    const int f4 = tid + j * 256;
    ((float4*)pool)[f4] = ((const float4*)pooled)[f4];
  }
  __syncthreads();

  float accb[B_];
#pragma unroll
  for (int b = 0; b < B_; ++b) accb[b] = 0.f;

#pragma unroll
  for (int i = 0; i < 4; ++i) {
    const float4 wv =
        *(const float4*)(W_cls + (size_t)c * D_ + i * 256 + lane * 4);
#pragma unroll
    for (int b = 0; b < B_; ++b) {
      const float4 p = *(const float4*)(&pool[b * D_ + i * 256 + lane * 4]);
      accb[b] = fmaf(wv.x, p.x,
                fmaf(wv.y, p.y, fmaf(wv.z, p.z, fmaf(wv.w, p.w, accb[b]))));
    }
  }
#pragma unroll
  for (int off = 1; off < 64; off <<= 1) {
#pragma unroll
    for (int b = 0; b < B_; ++b) accb[b] += __shfl_xor(accb[b], off);
  }
  if (lane < B_) out[(size_t)lane * NC_ + c] = accb[lane] + b_cls[c];
}

// ---------------------------------------------------------------------------
extern "C" void kernel_launch(void* const* d_in, const int* in_sizes, int n_in,
                              void* d_out, int out_size, void* d_ws,
                              size_t ws_size, hipStream_t stream) {
  const float* x = (const float*)d_in[0];
  const float* A_log = (const float*)d_in[1];
  const float* D_param = (const float*)d_in[2];
  const float* W_xproj = (const float*)d_in[3];
  const float* W_dt = (const float*)d_in[4];
  const float* b_dt = (const float*)d_in[5];
  const float* W_cls = (const float*)d_in[6];
  const float* b_cls = (const float*)d_in[7];
  float* out = (float*)d_out;

  // ws layout, flat, no aliasing (~79 MB; ws is ~268 MB per harness poison):
  float* ws_f = (float*)d_ws;
  float* xdb = ws_f;                               // 786,432 f
  float* part = xdb + (size_t)XP_M * 96;           // 6,291,456 f
  float* dtb = part + (size_t)XP_KS * XP_M * 96;   // 8,388,608 f
  float* summ = dtb + (size_t)XP_M * D_;           // 4,194,304 f
  float* sumx = summ + (size_t)CH8 * B_ * D_ * N_ * 4;  // 65,536 f
  float* pooled = sumx + (size_t)CH8 * B_ * D_;    // 8,192 f

  xproj_kernel<<<dim3(XP_M / XP_TM, XP_KS), dim3(256), 0, stream>>>(
      x, W_xproj, part);
  xreduce_kernel<<<dim3(XP_M * 96 / 4 / 256), dim3(256), 0, stream>>>(part,
                                                                      xdb);
  dt_kernel<<<dim3(XP_M / 16, 4), dim3(256), 0, stream>>>(xdb, W_dt, b_dt,
                                                          dtb);
  scan_kernel<<<dim3(B_ * 32, CH8), dim3(256), 0, stream>>>(x, xdb, dtb,
                                                            A_log, summ, sumx);
  combine_kernel<<<dim3(B_ * D_ * N_ / 256), dim3(256), 0, stream>>>(
      summ, sumx, D_param, pooled);
  cls_kernel<<<dim3(NC_ / 4), dim3(256), 0, stream>>>(pooled, W_cls, b_cls,
                                                      out);
}

// Round 7
// 114.389 us; speedup vs baseline: 1.5364x; 1.0880x over previous
//
#include <hip/hip_runtime.h>
#include <hip/hip_bf16.h>

// Problem constants
#define B_  8
#define L_  1024
#define D_  1024
#define N_  16
#define R_  64
#define NC_ 1000

#define XP_KS   8             // xproj split-K factor
#define XP_TM   64            // xproj rows per block
#define XP_KC   (D_ / XP_KS)  // 128 K per block
#define XP_M    (B_ * L_)     // 8192

#define CH8  8                // scan chunks over L
#define TCH8 (L_ / CH8)       // 128 timesteps per chunk
#define TB   32               // LDS staging batch (timesteps)

__device__ __forceinline__ float exp2_fast(float a) {
#if __has_builtin(__builtin_amdgcn_exp2f)
  return __builtin_amdgcn_exp2f(a);
#else
  float r;
  asm("v_exp_f32 %0, %1" : "=v"(r) : "v"(a));
  return r;
#endif
}

// ---------------------------------------------------------------------------
// Kernel 1a: partial xproj. part[ks][m][96] = sum_{k in slice ks} x[m][k]*W[c][k]
// ---------------------------------------------------------------------------
__global__ __launch_bounds__(256) void xproj_kernel(
    const float* __restrict__ x, const float* __restrict__ W,
    float* __restrict__ part) {
  __shared__ float xs[XP_TM][36];
  __shared__ float wt[32][100];
  const int tid = threadIdx.x;
  const int tx = tid & 7;
  const int ty = tid >> 3;
  const int m0 = blockIdx.x * XP_TM;
  const int ks = blockIdx.y;

  float acc[2][12];
#pragma unroll
  for (int r = 0; r < 2; ++r)
#pragma unroll
    for (int j = 0; j < 12; ++j) acc[r][j] = 0.f;

  for (int step = 0; step < XP_KC / 32; ++step) {
    const int kbase = ks * XP_KC + step * 32;
    __syncthreads();
#pragma unroll
    for (int j = 0; j < 2; ++j) {
      const int f4 = tid + j * 256;
      const int row = f4 >> 3, c4 = f4 & 7;
      float4 v = *(const float4*)(x + (size_t)(m0 + row) * D_ + kbase + c4 * 4);
      *(float4*)(&xs[row][c4 * 4]) = v;
    }
#pragma unroll
    for (int j = 0; j < 3; ++j) {
      const int idx = tid + j * 256;
      const int wr = idx >> 3, c4 = idx & 7;
      float4 v = *(const float4*)(W + (size_t)wr * D_ + kbase + c4 * 4);
      wt[c4 * 4 + 0][wr] = v.x;
      wt[c4 * 4 + 1][wr] = v.y;
      wt[c4 * 4 + 2][wr] = v.z;
      wt[c4 * 4 + 3][wr] = v.w;
    }
    __syncthreads();
#pragma unroll 4
    for (int kk = 0; kk < 32; ++kk) {
      const float a0 = xs[ty * 2 + 0][kk];
      const float a1 = xs[ty * 2 + 1][kk];
      const float4 b0 = *(const float4*)(&wt[kk][tx * 12 + 0]);
      const float4 b1 = *(const float4*)(&wt[kk][tx * 12 + 4]);
      const float4 b2 = *(const float4*)(&wt[kk][tx * 12 + 8]);
      acc[0][0] = fmaf(a0, b0.x, acc[0][0]);
      acc[0][1] = fmaf(a0, b0.y, acc[0][1]);
      acc[0][2] = fmaf(a0, b0.z, acc[0][2]);
      acc[0][3] = fmaf(a0, b0.w, acc[0][3]);
      acc[0][4] = fmaf(a0, b1.x, acc[0][4]);
      acc[0][5] = fmaf(a0, b1.y, acc[0][5]);
      acc[0][6] = fmaf(a0, b1.z, acc[0][6]);
      acc[0][7] = fmaf(a0, b1.w, acc[0][7]);
      acc[0][8] = fmaf(a0, b2.x, acc[0][8]);
      acc[0][9] = fmaf(a0, b2.y, acc[0][9]);
      acc[0][10] = fmaf(a0, b2.z, acc[0][10]);
      acc[0][11] = fmaf(a0, b2.w, acc[0][11]);
      acc[1][0] = fmaf(a1, b0.x, acc[1][0]);
      acc[1][1] = fmaf(a1, b0.y, acc[1][1]);
      acc[1][2] = fmaf(a1, b0.z, acc[1][2]);
      acc[1][3] = fmaf(a1, b0.w, acc[1][3]);
      acc[1][4] = fmaf(a1, b1.x, acc[1][4]);
      acc[1][5] = fmaf(a1, b1.y, acc[1][5]);
      acc[1][6] = fmaf(a1, b1.z, acc[1][6]);
      acc[1][7] = fmaf(a1, b1.w, acc[1][7]);
      acc[1][8] = fmaf(a1, b2.x, acc[1][8]);
      acc[1][9] = fmaf(a1, b2.y, acc[1][9]);
      acc[1][10] = fmaf(a1, b2.z, acc[1][10]);
      acc[1][11] = fmaf(a1, b2.w, acc[1][11]);
    }
  }
#pragma unroll
  for (int r = 0; r < 2; ++r) {
    float* p = part + ((size_t)ks * XP_M + m0 + ty * 2 + r) * 96 + tx * 12;
    *(float4*)(p + 0) = make_float4(acc[r][0], acc[r][1], acc[r][2], acc[r][3]);
    *(float4*)(p + 4) = make_float4(acc[r][4], acc[r][5], acc[r][6], acc[r][7]);
    *(float4*)(p + 8) = make_float4(acc[r][8], acc[r][9], acc[r][10], acc[r][11]);
  }
}

// ---------------------------------------------------------------------------
// Kernel 1b: reduce 8 K-slice partials -> xdb[m][96].
// ---------------------------------------------------------------------------
__global__ __launch_bounds__(256) void xreduce_kernel(
    const float* __restrict__ part, float* __restrict__ xdb) {
  const size_t gidx = (size_t)blockIdx.x * 256 + threadIdx.x;
  const float4* p4 = (const float4*)part;
  const size_t stride = (size_t)XP_M * 96 / 4;
  float4 s = p4[gidx];
#pragma unroll
  for (int ks = 1; ks < XP_KS; ++ks) {
    const float4 v = p4[(size_t)ks * stride + gidx];
    s.x += v.x; s.y += v.y; s.z += v.z; s.w += v.w;
  }
  ((float4*)xdb)[gidx] = s;
}

// ---------------------------------------------------------------------------
// Kernel 2: dt (full batch). dtb[m][d] = softplus(dot(xdb[m][0:64], W_dt[d]) +
// b_dt[d]). __launch_bounds__(256,4) keeps w[16] register-resident.
// ---------------------------------------------------------------------------
__global__ __launch_bounds__(256, 4) void dt_kernel(
    const float* __restrict__ xdb, const float* __restrict__ W_dt,
    const float* __restrict__ b_dt, float* __restrict__ dtb) {
  __shared__ float dtr[16][64];
  const int tid = threadIdx.x;
  const int d = blockIdx.y * 256 + tid;
  const int m0 = blockIdx.x * 16;

  float4 w[16];
#pragma unroll
  for (int i = 0; i < 16; ++i)
    w[i] = *(const float4*)(W_dt + (size_t)d * R_ + i * 4);
  const float bd = b_dt[d];

  {
    const int row = tid >> 4, c4 = tid & 15;
    *(float4*)(&dtr[row][c4 * 4]) =
        *(const float4*)(xdb + (size_t)(m0 + row) * 96 + c4 * 4);
  }
  __syncthreads();

#pragma unroll 4
  for (int row = 0; row < 16; ++row) {
    float a0 = 0.f, a1 = 0.f, a2 = 0.f, a3 = 0.f;
#pragma unroll
    for (int rc = 0; rc < 16; ++rc) {
      const float4 v = *(const float4*)(&dtr[row][rc * 4]);
      a0 = fmaf(v.x, w[rc].x, a0);
      a1 = fmaf(v.y, w[rc].y, a1);
      a2 = fmaf(v.z, w[rc].z, a2);
      a3 = fmaf(v.w, w[rc].w, a3);
    }
    const float s = bd + ((a0 + a1) + (a2 + a3));
    const float sp = fmaxf(s, 0.f) + __logf(1.0f + __expf(-fabsf(s)));
    dtb[(size_t)(m0 + row) * D_ + d] = sp;
  }
}

// ---------------------------------------------------------------------------
// Kernel 3: LDS-staged chunked scan, instruction-dieted.
// Block: 256 = 16 dl x 16 n, thread owns ADJACENT d pair (d0+2dl, d0+2dl+1).
// Staging precomputes dtx = dt*x (kills per-n-redundant mul) and accumulates
// xsum partials (kills inner add + xv read). Inner loop: 3 ds_read_b64
// (dt pair, dtx pair, interleaved B/C) + 12 VALU + 2 exp per 2 units
// (was 6 reads + 14 VALU + 2 trans + 2 muls' worth). exp2 direct with
// log2e folded into Aval (saves __expf's hidden mul).
// ---------------------------------------------------------------------------
__global__ __launch_bounds__(256) void scan_kernel(
    const float* __restrict__ x, const float* __restrict__ xdb,
    const float* __restrict__ dtb, const float* __restrict__ A_log,
    float* __restrict__ summ, float* __restrict__ sumx) {
  __shared__ float dts[TB][32];
  __shared__ float dtx[TB][32];
  __shared__ float bcs[TB][34];  // pad 34: conflict-free scatter, b64-aligned
  const int tid = threadIdx.x;
  const int n = tid & 15;
  const int dl = tid >> 4;          // 0..15
  const int b = blockIdx.x >> 5;    // 0..7
  const int dtile = blockIdx.x & 31;
  const int c = blockIdx.y;         // 0..7
  const int d0 = dtile * 32;
  const int da = d0 + 2 * dl, db = da + 1;

  const float Av0 = -__expf(A_log[(size_t)da * N_ + n]) * 1.44269504089f;
  const float Av1 = -__expf(A_log[(size_t)db * N_ + n]) * 1.44269504089f;

  const int t0 = c * TCH8;
  float cumP0 = 1.f, loc0 = 0.f, S10 = 0.f, S20 = 0.f;
  float cumP1 = 1.f, loc1 = 0.f, S11 = 0.f, S21 = 0.f;
  float xp0 = 0.f, xp1 = 0.f, xp2 = 0.f, xp3 = 0.f;  // xsum partials

  const int srow = tid >> 3, sc4 = (tid & 7) * 4;  // 32 rows x 32 cols
  // interleave position for B/C: col j<16 (B[j]) -> 2j ; j>=16 (C[j-16]) -> 2(j-16)+1
  const int bpos = ((sc4 * 2) & 31) + (sc4 >> 4);

  for (int tb = 0; tb < TCH8; tb += TB) {
    const int tbase = t0 + tb;
    __syncthreads();
    {
      const size_t g = ((size_t)b * L_ + tbase + srow) * D_ + d0 + sc4;
      const float4 xv = *(const float4*)(x + g);
      const float4 dv = *(const float4*)(dtb + g);
      *(float4*)(&dts[srow][sc4]) = dv;
      *(float4*)(&dtx[srow][sc4]) =
          make_float4(xv.x * dv.x, xv.y * dv.y, xv.z * dv.z, xv.w * dv.w);
      xp0 += xv.x; xp1 += xv.y; xp2 += xv.z; xp3 += xv.w;
      const size_t gb = ((size_t)b * L_ + tbase + srow) * 96 + 64 + sc4;
      const float4 bc = *(const float4*)(xdb + gb);
      bcs[srow][bpos + 0] = bc.x;
      bcs[srow][bpos + 2] = bc.y;
      bcs[srow][bpos + 4] = bc.z;
      bcs[srow][bpos + 6] = bc.w;
    }
    __syncthreads();
#pragma unroll
    for (int tt = 0; tt < TB; ++tt) {
      const float2 bv = *(const float2*)(&bcs[tt][2 * n]);   // (B[n], C[n])
      const float2 dv = *(const float2*)(&dts[tt][2 * dl]);
      const float2 px = *(const float2*)(&dtx[tt][2 * dl]);
      const float e0 = exp2_fast(dv.x * Av0);
      cumP0 *= e0;
      loc0 = fmaf(e0, loc0, px.x * bv.x);
      S10 = fmaf(cumP0, bv.y, S10);
      S20 = fmaf(loc0, bv.y, S20);
      const float e1 = exp2_fast(dv.y * Av1);
      cumP1 *= e1;
      loc1 = fmaf(e1, loc1, px.y * bv.x);
      S11 = fmaf(cumP1, bv.y, S11);
      S21 = fmaf(loc1, bv.y, S21);
    }
  }
  const size_t si0 = (((size_t)c * B_ + b) * D_ + da) * N_ + n;
  const size_t si1 = (((size_t)c * B_ + b) * D_ + db) * N_ + n;
  ((float4*)summ)[si0] = make_float4(cumP0, S10, S20, loc0);
  ((float4*)summ)[si1] = make_float4(cumP1, S11, S21, loc1);

  // xsum: per-thread partials cover cols sc4..sc4+3, rows {srow + k*TB} of
  // this chunk. Reduce over the 32 srow-threads via LDS (reuse dtx).
  __syncthreads();
  *(float4*)(&dtx[srow][sc4]) = make_float4(xp0, xp1, xp2, xp3);
  __syncthreads();
  if (tid < 32) {
    float s = 0.f;
#pragma unroll
    for (int r = 0; r < 32; ++r) s += dtx[r][tid];
    sumx[((size_t)c * B_ + b) * D_ + d0 + tid] = s;
  }
}

// ---------------------------------------------------------------------------
// Kernel 3b: exact sequential chunk combine + n-reduce -> pooled.
// ---------------------------------------------------------------------------
__global__ __launch_bounds__(256) void combine_kernel(
    const float* __restrict__ summ, const float* __restrict__ sumx,
    const float* __restrict__ D_param, float* __restrict__ pooled) {
  const int gid = blockIdx.x * 256 + threadIdx.x;  // 0..131071
  const int n = gid & 15;
  const int d = (gid >> 4) & (D_ - 1);
  const int b = gid >> 14;  // 0..7
  float hin = 0.f, acc = 0.f;
  const float4* s4 = (const float4*)summ;
#pragma unroll
  for (int c = 0; c < CH8; ++c) {
    const float4 f = s4[(((size_t)c * B_ + b) * D_ + d) * N_ + n];
    acc = fmaf(hin, f.y, acc) + f.z;
    hin = fmaf(f.x, hin, f.w);
  }
  acc += __shfl_xor(acc, 1);
  acc += __shfl_xor(acc, 2);
  acc += __shfl_xor(acc, 4);
  acc += __shfl_xor(acc, 8);
  if (n == 0) {
    float xst = 0.f;
#pragma unroll
    for (int c = 0; c < CH8; ++c)
      xst += sumx[((size_t)c * B_ + b) * D_ + d];
    pooled[(size_t)b * D_ + d] =
        (acc + D_param[d] * xst) * (1.0f / (float)L_);
  }
}

// ---------------------------------------------------------------------------
// Kernel 4: logits. One wave per class; all 8 batches from LDS-staged pooled.
// ---------------------------------------------------------------------------
__global__ __launch_bounds__(256) void cls_kernel(
    const float* __restrict__ pooled, const float* __restrict__ W_cls,
    const float* __restrict__ b_cls, float* __restrict__ out) {
  __shared__ float pool[B_ * D_];  // 32 KB
  const int tid = threadIdx.x;
  const int c = blockIdx.x * 4 + (tid >> 6);
  const int lane = tid & 63;

#pragma unroll
  for (int j = 0; j < 8; ++j) {
    const int f4 = tid + j * 256;
    ((float4*)pool)[f4] = ((const float4*)pooled)[f4];
  }
  __syncthreads();

  float accb[B_];
#pragma unroll
  for (int b = 0; b < B_; ++b) accb[b] = 0.f;

#pragma unroll
  for (int i = 0; i < 4; ++i) {
    const float4 wv =
        *(const float4*)(W_cls + (size_t)c * D_ + i * 256 + lane * 4);
#pragma unroll
    for (int b = 0; b < B_; ++b) {
      const float4 p = *(const float4*)(&pool[b * D_ + i * 256 + lane * 4]);
      accb[b] = fmaf(wv.x, p.x,
                fmaf(wv.y, p.y, fmaf(wv.z, p.z, fmaf(wv.w, p.w, accb[b]))));
    }
  }
#pragma unroll
  for (int off = 1; off < 64; off <<= 1) {
#pragma unroll
    for (int b = 0; b < B_; ++b) accb[b] += __shfl_xor(accb[b], off);
  }
  if (lane < B_) out[(size_t)lane * NC_ + c] = accb[lane] + b_cls[c];
}

// ---------------------------------------------------------------------------
extern "C" void kernel_launch(void* const* d_in, const int* in_sizes, int n_in,
                              void* d_out, int out_size, void* d_ws,
                              size_t ws_size, hipStream_t stream) {
  const float* x = (const float*)d_in[0];
  const float* A_log = (const float*)d_in[1];
  const float* D_param = (const float*)d_in[2];
  const float* W_xproj = (const float*)d_in[3];
  const float* W_dt = (const float*)d_in[4];
  const float* b_dt = (const float*)d_in[5];
  const float* W_cls = (const float*)d_in[6];
  const float* b_cls = (const float*)d_in[7];
  float* out = (float*)d_out;

  // ws layout, flat, no aliasing (~79 MB of ~268 MB available):
  float* ws_f = (float*)d_ws;
  float* xdb = ws_f;                               // 786,432 f
  float* part = xdb + (size_t)XP_M * 96;           // 6,291,456 f
  float* dtb = part + (size_t)XP_KS * XP_M * 96;   // 8,388,608 f
  float* summ = dtb + (size_t)XP_M * D_;           // 4,194,304 f
  float* sumx = summ + (size_t)CH8 * B_ * D_ * N_ * 4;  // 65,536 f
  float* pooled = sumx + (size_t)CH8 * B_ * D_;    // 8,192 f

  xproj_kernel<<<dim3(XP_M / XP_TM, XP_KS), dim3(256), 0, stream>>>(
      x, W_xproj, part);
  xreduce_kernel<<<dim3(XP_M * 96 / 4 / 256), dim3(256), 0, stream>>>(part,
                                                                      xdb);
  dt_kernel<<<dim3(XP_M / 16, 4), dim3(256), 0, stream>>>(xdb, W_dt, b_dt,
                                                          dtb);
  scan_kernel<<<dim3(B_ * 32, CH8), dim3(256), 0, stream>>>(x, xdb, dtb,
                                                            A_log, summ, sumx);
  combine_kernel<<<dim3(B_ * D_ * N_ / 256), dim3(256), 0, stream>>>(
      summ, sumx, D_param, pooled);
  cls_kernel<<<dim3(NC_ / 4), dim3(256), 0, stream>>>(pooled, W_cls, b_cls,
                                                      out);
}

// Round 8
// 103.106 us; speedup vs baseline: 1.7046x; 1.1094x over previous
//
#include <hip/hip_runtime.h>
#include <hip/hip_bf16.h>

// Problem constants
#define B_  8
#define L_  1024
#define D_  1024
#define N_  16
#define R_  64
#define NC_ 1000

#define XP_KS   8             // xproj split-K factor
#define XP_TM   64            // xproj rows per block
#define XP_KC   (D_ / XP_KS)  // 128 K per block
#define XP_M    (B_ * L_)     // 8192

#define CH8  8                // scan chunks over L
#define TCH8 (L_ / CH8)       // 128 timesteps per chunk
#define TB   32               // LDS staging batch (timesteps)

__device__ __forceinline__ float exp2_fast(float a) {
#if __has_builtin(__builtin_amdgcn_exp2f)
  return __builtin_amdgcn_exp2f(a);
#else
  float r;
  asm("v_exp_f32 %0, %1" : "=v"(r) : "v"(a));
  return r;
#endif
}

// ---------------------------------------------------------------------------
// Kernel 1a: partial xproj. part[ks][m][96] = sum_{k in slice ks} x[m][k]*W[c][k]
// ---------------------------------------------------------------------------
__global__ __launch_bounds__(256) void xproj_kernel(
    const float* __restrict__ x, const float* __restrict__ W,
    float* __restrict__ part) {
  __shared__ float xs[XP_TM][36];
  __shared__ float wt[32][100];
  const int tid = threadIdx.x;
  const int tx = tid & 7;
  const int ty = tid >> 3;
  const int m0 = blockIdx.x * XP_TM;
  const int ks = blockIdx.y;

  float acc[2][12];
#pragma unroll
  for (int r = 0; r < 2; ++r)
#pragma unroll
    for (int j = 0; j < 12; ++j) acc[r][j] = 0.f;

  for (int step = 0; step < XP_KC / 32; ++step) {
    const int kbase = ks * XP_KC + step * 32;
    __syncthreads();
#pragma unroll
    for (int j = 0; j < 2; ++j) {
      const int f4 = tid + j * 256;
      const int row = f4 >> 3, c4 = f4 & 7;
      float4 v = *(const float4*)(x + (size_t)(m0 + row) * D_ + kbase + c4 * 4);
      *(float4*)(&xs[row][c4 * 4]) = v;
    }
#pragma unroll
    for (int j = 0; j < 3; ++j) {
      const int idx = tid + j * 256;
      const int wr = idx >> 3, c4 = idx & 7;
      float4 v = *(const float4*)(W + (size_t)wr * D_ + kbase + c4 * 4);
      wt[c4 * 4 + 0][wr] = v.x;
      wt[c4 * 4 + 1][wr] = v.y;
      wt[c4 * 4 + 2][wr] = v.z;
      wt[c4 * 4 + 3][wr] = v.w;
    }
    __syncthreads();
#pragma unroll 4
    for (int kk = 0; kk < 32; ++kk) {
      const float a0 = xs[ty * 2 + 0][kk];
      const float a1 = xs[ty * 2 + 1][kk];
      const float4 b0 = *(const float4*)(&wt[kk][tx * 12 + 0]);
      const float4 b1 = *(const float4*)(&wt[kk][tx * 12 + 4]);
      const float4 b2 = *(const float4*)(&wt[kk][tx * 12 + 8]);
      acc[0][0] = fmaf(a0, b0.x, acc[0][0]);
      acc[0][1] = fmaf(a0, b0.y, acc[0][1]);
      acc[0][2] = fmaf(a0, b0.z, acc[0][2]);
      acc[0][3] = fmaf(a0, b0.w, acc[0][3]);
      acc[0][4] = fmaf(a0, b1.x, acc[0][4]);
      acc[0][5] = fmaf(a0, b1.y, acc[0][5]);
      acc[0][6] = fmaf(a0, b1.z, acc[0][6]);
      acc[0][7] = fmaf(a0, b1.w, acc[0][7]);
      acc[0][8] = fmaf(a0, b2.x, acc[0][8]);
      acc[0][9] = fmaf(a0, b2.y, acc[0][9]);
      acc[0][10] = fmaf(a0, b2.z, acc[0][10]);
      acc[0][11] = fmaf(a0, b2.w, acc[0][11]);
      acc[1][0] = fmaf(a1, b0.x, acc[1][0]);
      acc[1][1] = fmaf(a1, b0.y, acc[1][1]);
      acc[1][2] = fmaf(a1, b0.z, acc[1][2]);
      acc[1][3] = fmaf(a1, b0.w, acc[1][3]);
      acc[1][4] = fmaf(a1, b1.x, acc[1][4]);
      acc[1][5] = fmaf(a1, b1.y, acc[1][5]);
      acc[1][6] = fmaf(a1, b1.z, acc[1][6]);
      acc[1][7] = fmaf(a1, b1.w, acc[1][7]);
      acc[1][8] = fmaf(a1, b2.x, acc[1][8]);
      acc[1][9] = fmaf(a1, b2.y, acc[1][9]);
      acc[1][10] = fmaf(a1, b2.z, acc[1][10]);
      acc[1][11] = fmaf(a1, b2.w, acc[1][11]);
    }
  }
#pragma unroll
  for (int r = 0; r < 2; ++r) {
    float* p = part + ((size_t)ks * XP_M + m0 + ty * 2 + r) * 96 + tx * 12;
    *(float4*)(p + 0) = make_float4(acc[r][0], acc[r][1], acc[r][2], acc[r][3]);
    *(float4*)(p + 4) = make_float4(acc[r][4], acc[r][5], acc[r][6], acc[r][7]);
    *(float4*)(p + 8) = make_float4(acc[r][8], acc[r][9], acc[r][10], acc[r][11]);
  }
}

// ---------------------------------------------------------------------------
// Kernel 1b: reduce 8 K-slice partials -> xdb[m][96].
// ---------------------------------------------------------------------------
__global__ __launch_bounds__(256) void xreduce_kernel(
    const float* __restrict__ part, float* __restrict__ xdb) {
  const size_t gidx = (size_t)blockIdx.x * 256 + threadIdx.x;
  const float4* p4 = (const float4*)part;
  const size_t stride = (size_t)XP_M * 96 / 4;
  float4 s = p4[gidx];
#pragma unroll
  for (int ks = 1; ks < XP_KS; ++ks) {
    const float4 v = p4[(size_t)ks * stride + gidx];
    s.x += v.x; s.y += v.y; s.z += v.z; s.w += v.w;
  }
  ((float4*)xdb)[gidx] = s;
}

// ---------------------------------------------------------------------------
// Kernel 2: dt GEMM, both operands via LDS (no register-residency gamble —
// round-7 showed the allocator rematerializes w[16] from L2: VGPR=56, 44 us).
// Tile 64m x 64d, K=64 whole. Stage xdb^T (xst[k][m]) and W_dt^T (wt[k][d]),
// pad 68 (b128-aligned, 2-way banks). Thread = 4m x 4d; inner k-step =
// 2 broadcast ds_read_b128 (const base + k*272 imm offset) + 16 fma.
// Grid (128,16) = 2048 blocks, 34 KB LDS -> 4 blocks/CU.
// ---------------------------------------------------------------------------
__global__ __launch_bounds__(256) void dt_kernel(
    const float* __restrict__ xdb, const float* __restrict__ W_dt,
    const float* __restrict__ b_dt, float* __restrict__ dtb) {
  __shared__ float xst[64][68];
  __shared__ float wt[64][68];
  const int tid = threadIdx.x;
  const int tx = tid & 15;   // d-quad
  const int ty = tid >> 4;   // m-quad
  const int m0 = blockIdx.x * 64;
  const int d0 = blockIdx.y * 64;

  {  // stage transposed: qc = k-quad, rows = m (or d) local
    const int qc = tid & 15, rr = tid >> 4;
#pragma unroll
    for (int j = 0; j < 4; ++j) {
      const int row = rr + j * 16;  // 0..63
      const float4 a = *(const float4*)(xdb + (size_t)(m0 + row) * 96 + qc * 4);
      xst[qc * 4 + 0][row] = a.x;
      xst[qc * 4 + 1][row] = a.y;
      xst[qc * 4 + 2][row] = a.z;
      xst[qc * 4 + 3][row] = a.w;
      const float4 w = *(const float4*)(W_dt + (size_t)(d0 + row) * R_ + qc * 4);
      wt[qc * 4 + 0][row] = w.x;
      wt[qc * 4 + 1][row] = w.y;
      wt[qc * 4 + 2][row] = w.z;
      wt[qc * 4 + 3][row] = w.w;
    }
  }
  __syncthreads();

  float acc[4][4];
#pragma unroll
  for (int i = 0; i < 4; ++i)
#pragma unroll
    for (int j = 0; j < 4; ++j) acc[i][j] = 0.f;

#pragma unroll
  for (int k = 0; k < 64; ++k) {
    const float4 bq = *(const float4*)(&wt[k][tx * 4]);
    const float4 aq = *(const float4*)(&xst[k][ty * 4]);
#pragma unroll
    for (int mi = 0; mi < 4; ++mi) {
      const float a = (mi == 0) ? aq.x : (mi == 1) ? aq.y : (mi == 2) ? aq.z : aq.w;
      acc[mi][0] = fmaf(a, bq.x, acc[mi][0]);
      acc[mi][1] = fmaf(a, bq.y, acc[mi][1]);
      acc[mi][2] = fmaf(a, bq.z, acc[mi][2]);
      acc[mi][3] = fmaf(a, bq.w, acc[mi][3]);
    }
  }

  const float4 bd = *(const float4*)(b_dt + d0 + tx * 4);
#pragma unroll
  for (int mi = 0; mi < 4; ++mi) {
    float4 o;
    float s;
    s = acc[mi][0] + bd.x;
    o.x = fmaxf(s, 0.f) + __logf(1.0f + __expf(-fabsf(s)));
    s = acc[mi][1] + bd.y;
    o.y = fmaxf(s, 0.f) + __logf(1.0f + __expf(-fabsf(s)));
    s = acc[mi][2] + bd.z;
    o.z = fmaxf(s, 0.f) + __logf(1.0f + __expf(-fabsf(s)));
    s = acc[mi][3] + bd.w;
    o.w = fmaxf(s, 0.f) + __logf(1.0f + __expf(-fabsf(s)));
    *(float4*)(dtb + (size_t)(m0 + ty * 4 + mi) * D_ + d0 + tx * 4) = o;
  }
}

// ---------------------------------------------------------------------------
// Kernel 3: LDS-staged chunked scan, instruction-dieted (round 7 version).
// ---------------------------------------------------------------------------
__global__ __launch_bounds__(256) void scan_kernel(
    const float* __restrict__ x, const float* __restrict__ xdb,
    const float* __restrict__ dtb, const float* __restrict__ A_log,
    float* __restrict__ summ, float* __restrict__ sumx) {
  __shared__ float dts[TB][32];
  __shared__ float dtx[TB][32];
  __shared__ float bcs[TB][34];  // pad 34: conflict-free scatter, b64-aligned
  const int tid = threadIdx.x;
  const int n = tid & 15;
  const int dl = tid >> 4;          // 0..15
  const int b = blockIdx.x >> 5;    // 0..7
  const int dtile = blockIdx.x & 31;
  const int c = blockIdx.y;         // 0..7
  const int d0 = dtile * 32;
  const int da = d0 + 2 * dl, db = da + 1;

  const float Av0 = -__expf(A_log[(size_t)da * N_ + n]) * 1.44269504089f;
  const float Av1 = -__expf(A_log[(size_t)db * N_ + n]) * 1.44269504089f;

  const int t0 = c * TCH8;
  float cumP0 = 1.f, loc0 = 0.f, S10 = 0.f, S20 = 0.f;
  float cumP1 = 1.f, loc1 = 0.f, S11 = 0.f, S21 = 0.f;
  float xp0 = 0.f, xp1 = 0.f, xp2 = 0.f, xp3 = 0.f;  // xsum partials

  const int srow = tid >> 3, sc4 = (tid & 7) * 4;  // 32 rows x 32 cols
  const int bpos = ((sc4 * 2) & 31) + (sc4 >> 4);

  for (int tb = 0; tb < TCH8; tb += TB) {
    const int tbase = t0 + tb;
    __syncthreads();
    {
      const size_t g = ((size_t)b * L_ + tbase + srow) * D_ + d0 + sc4;
      const float4 xv = *(const float4*)(x + g);
      const float4 dv = *(const float4*)(dtb + g);
      *(float4*)(&dts[srow][sc4]) = dv;
      *(float4*)(&dtx[srow][sc4]) =
          make_float4(xv.x * dv.x, xv.y * dv.y, xv.z * dv.z, xv.w * dv.w);
      xp0 += xv.x; xp1 += xv.y; xp2 += xv.z; xp3 += xv.w;
      const size_t gb = ((size_t)b * L_ + tbase + srow) * 96 + 64 + sc4;
      const float4 bc = *(const float4*)(xdb + gb);
      bcs[srow][bpos + 0] = bc.x;
      bcs[srow][bpos + 2] = bc.y;
      bcs[srow][bpos + 4] = bc.z;
      bcs[srow][bpos + 6] = bc.w;
    }
    __syncthreads();
#pragma unroll
    for (int tt = 0; tt < TB; ++tt) {
      const float2 bv = *(const float2*)(&bcs[tt][2 * n]);   // (B[n], C[n])
      const float2 dv = *(const float2*)(&dts[tt][2 * dl]);
      const float2 px = *(const float2*)(&dtx[tt][2 * dl]);
      const float e0 = exp2_fast(dv.x * Av0);
      cumP0 *= e0;
      loc0 = fmaf(e0, loc0, px.x * bv.x);
      S10 = fmaf(cumP0, bv.y, S10);
      S20 = fmaf(loc0, bv.y, S20);
      const float e1 = exp2_fast(dv.y * Av1);
      cumP1 *= e1;
      loc1 = fmaf(e1, loc1, px.y * bv.x);
      S11 = fmaf(cumP1, bv.y, S11);
      S21 = fmaf(loc1, bv.y, S21);
    }
  }
  const size_t si0 = (((size_t)c * B_ + b) * D_ + da) * N_ + n;
  const size_t si1 = (((size_t)c * B_ + b) * D_ + db) * N_ + n;
  ((float4*)summ)[si0] = make_float4(cumP0, S10, S20, loc0);
  ((float4*)summ)[si1] = make_float4(cumP1, S11, S21, loc1);

  __syncthreads();
  *(float4*)(&dtx[srow][sc4]) = make_float4(xp0, xp1, xp2, xp3);
  __syncthreads();
  if (tid < 32) {
    float s = 0.f;
#pragma unroll
    for (int r = 0; r < 32; ++r) s += dtx[r][tid];
    sumx[((size_t)c * B_ + b) * D_ + d0 + tid] = s;
  }
}

// ---------------------------------------------------------------------------
// Kernel 3b: exact sequential chunk combine + n-reduce -> pooled.
// ---------------------------------------------------------------------------
__global__ __launch_bounds__(256) void combine_kernel(
    const float* __restrict__ summ, const float* __restrict__ sumx,
    const float* __restrict__ D_param, float* __restrict__ pooled) {
  const int gid = blockIdx.x * 256 + threadIdx.x;  // 0..131071
  const int n = gid & 15;
  const int d = (gid >> 4) & (D_ - 1);
  const int b = gid >> 14;  // 0..7
  float hin = 0.f, acc = 0.f;
  const float4* s4 = (const float4*)summ;
#pragma unroll
  for (int c = 0; c < CH8; ++c) {
    const float4 f = s4[(((size_t)c * B_ + b) * D_ + d) * N_ + n];
    acc = fmaf(hin, f.y, acc) + f.z;
    hin = fmaf(f.x, hin, f.w);
  }
  acc += __shfl_xor(acc, 1);
  acc += __shfl_xor(acc, 2);
  acc += __shfl_xor(acc, 4);
  acc += __shfl_xor(acc, 8);
  if (n == 0) {
    float xst = 0.f;
#pragma unroll
    for (int c = 0; c < CH8; ++c)
      xst += sumx[((size_t)c * B_ + b) * D_ + d];
    pooled[(size_t)b * D_ + d] =
        (acc + D_param[d] * xst) * (1.0f / (float)L_);
  }
}

// ---------------------------------------------------------------------------
// Kernel 4: logits. One wave per class; all 8 batches from LDS-staged pooled.
// ---------------------------------------------------------------------------
__global__ __launch_bounds__(256) void cls_kernel(
    const float* __restrict__ pooled, const float* __restrict__ W_cls,
    const float* __restrict__ b_cls, float* __restrict__ out) {
  __shared__ float pool[B_ * D_];  // 32 KB
  const int tid = threadIdx.x;
  const int c = blockIdx.x * 4 + (tid >> 6);
  const int lane = tid & 63;

#pragma unroll
  for (int j = 0; j < 8; ++j) {
    const int f4 = tid + j * 256;
    ((float4*)pool)[f4] = ((const float4*)pooled)[f4];
  }
  __syncthreads();

  float accb[B_];
#pragma unroll
  for (int b = 0; b < B_; ++b) accb[b] = 0.f;

#pragma unroll
  for (int i = 0; i < 4; ++i) {
    const float4 wv =
        *(const float4*)(W_cls + (size_t)c * D_ + i * 256 + lane * 4);
#pragma unroll
    for (int b = 0; b < B_; ++b) {
      const float4 p = *(const float4*)(&pool[b * D_ + i * 256 + lane * 4]);
      accb[b] = fmaf(wv.x, p.x,
                fmaf(wv.y, p.y, fmaf(wv.z, p.z, fmaf(wv.w, p.w, accb[b]))));
    }
  }
#pragma unroll
  for (int off = 1; off < 64; off <<= 1) {
#pragma unroll
    for (int b = 0; b < B_; ++b) accb[b] += __shfl_xor(accb[b], off);
  }
  if (lane < B_) out[(size_t)lane * NC_ + c] = accb[lane] + b_cls[c];
}

// ---------------------------------------------------------------------------
extern "C" void kernel_launch(void* const* d_in, const int* in_sizes, int n_in,
                              void* d_out, int out_size, void* d_ws,
                              size_t ws_size, hipStream_t stream) {
  const float* x = (const float*)d_in[0];
  const float* A_log = (const float*)d_in[1];
  const float* D_param = (const float*)d_in[2];
  const float* W_xproj = (const float*)d_in[3];
  const float* W_dt = (const float*)d_in[4];
  const float* b_dt = (const float*)d_in[5];
  const float* W_cls = (const float*)d_in[6];
  const float* b_cls = (const float*)d_in[7];
  float* out = (float*)d_out;

  // ws layout, flat, no aliasing (~79 MB of ~268 MB available):
  float* ws_f = (float*)d_ws;
  float* xdb = ws_f;                               // 786,432 f
  float* part = xdb + (size_t)XP_M * 96;           // 6,291,456 f
  float* dtb = part + (size_t)XP_KS * XP_M * 96;   // 8,388,608 f
  float* summ = dtb + (size_t)XP_M * D_;           // 4,194,304 f
  float* sumx = summ + (size_t)CH8 * B_ * D_ * N_ * 4;  // 65,536 f
  float* pooled = sumx + (size_t)CH8 * B_ * D_;    // 8,192 f

  xproj_kernel<<<dim3(XP_M / XP_TM, XP_KS), dim3(256), 0, stream>>>(
      x, W_xproj, part);
  xreduce_kernel<<<dim3(XP_M * 96 / 4 / 256), dim3(256), 0, stream>>>(part,
                                                                      xdb);
  dt_kernel<<<dim3(XP_M / 64, D_ / 64), dim3(256), 0, stream>>>(xdb, W_dt,
                                                                b_dt, dtb);
  scan_kernel<<<dim3(B_ * 32, CH8), dim3(256), 0, stream>>>(x, xdb, dtb,
                                                            A_log, summ, sumx);
  combine_kernel<<<dim3(B_ * D_ * N_ / 256), dim3(256), 0, stream>>>(
      summ, sumx, D_param, pooled);
  cls_kernel<<<dim3(NC_ / 4), dim3(256), 0, stream>>>(pooled, W_cls, b_cls,
                                                      out);
}

// Round 9
// 102.794 us; speedup vs baseline: 1.7098x; 1.0030x over previous
//
#include <hip/hip_runtime.h>
#include <hip/hip_bf16.h>

// Problem constants
#define B_  8
#define L_  1024
#define D_  1024
#define N_  16
#define R_  64
#define NC_ 1000

#define XP_KS   8             // xproj split-K factor
#define XP_TM   64            // xproj rows per block
#define XP_KC   (D_ / XP_KS)  // 128 K per block
#define XP_M    (B_ * L_)     // 8192

#define CH8  8                // scan chunks over L
#define TCH8 (L_ / CH8)       // 128 timesteps per chunk
#define TB   32               // LDS staging batch (timesteps)

__device__ __forceinline__ float exp2_fast(float a) {
#if __has_builtin(__builtin_amdgcn_exp2f)
  return __builtin_amdgcn_exp2f(a);
#else
  float r;
  asm("v_exp_f32 %0, %1" : "=v"(r) : "v"(a));
  return r;
#endif
}

// ---------------------------------------------------------------------------
// Kernel 1a: partial xproj. part[ks][m][96] = sum_{k in slice ks} x[m][k]*W[c][k]
// ---------------------------------------------------------------------------
__global__ __launch_bounds__(256) void xproj_kernel(
    const float* __restrict__ x, const float* __restrict__ W,
    float* __restrict__ part) {
  __shared__ float xs[XP_TM][36];
  __shared__ float wt[32][100];
  const int tid = threadIdx.x;
  const int tx = tid & 7;
  const int ty = tid >> 3;
  const int m0 = blockIdx.x * XP_TM;
  const int ks = blockIdx.y;

  float acc[2][12];
#pragma unroll
  for (int r = 0; r < 2; ++r)
#pragma unroll
    for (int j = 0; j < 12; ++j) acc[r][j] = 0.f;

  for (int step = 0; step < XP_KC / 32; ++step) {
    const int kbase = ks * XP_KC + step * 32;
    __syncthreads();
#pragma unroll
    for (int j = 0; j < 2; ++j) {
      const int f4 = tid + j * 256;
      const int row = f4 >> 3, c4 = f4 & 7;
      float4 v = *(const float4*)(x + (size_t)(m0 + row) * D_ + kbase + c4 * 4);
      *(float4*)(&xs[row][c4 * 4]) = v;
    }
#pragma unroll
    for (int j = 0; j < 3; ++j) {
      const int idx = tid + j * 256;
      const int wr = idx >> 3, c4 = idx & 7;
      float4 v = *(const float4*)(W + (size_t)wr * D_ + kbase + c4 * 4);
      wt[c4 * 4 + 0][wr] = v.x;
      wt[c4 * 4 + 1][wr] = v.y;
      wt[c4 * 4 + 2][wr] = v.z;
      wt[c4 * 4 + 3][wr] = v.w;
    }
    __syncthreads();
#pragma unroll 4
    for (int kk = 0; kk < 32; ++kk) {
      const float a0 = xs[ty * 2 + 0][kk];
      const float a1 = xs[ty * 2 + 1][kk];
      const float4 b0 = *(const float4*)(&wt[kk][tx * 12 + 0]);
      const float4 b1 = *(const float4*)(&wt[kk][tx * 12 + 4]);
      const float4 b2 = *(const float4*)(&wt[kk][tx * 12 + 8]);
      acc[0][0] = fmaf(a0, b0.x, acc[0][0]);
      acc[0][1] = fmaf(a0, b0.y, acc[0][1]);
      acc[0][2] = fmaf(a0, b0.z, acc[0][2]);
      acc[0][3] = fmaf(a0, b0.w, acc[0][3]);
      acc[0][4] = fmaf(a0, b1.x, acc[0][4]);
      acc[0][5] = fmaf(a0, b1.y, acc[0][5]);
      acc[0][6] = fmaf(a0, b1.z, acc[0][6]);
      acc[0][7] = fmaf(a0, b1.w, acc[0][7]);
      acc[0][8] = fmaf(a0, b2.x, acc[0][8]);
      acc[0][9] = fmaf(a0, b2.y, acc[0][9]);
      acc[0][10] = fmaf(a0, b2.z, acc[0][10]);
      acc[0][11] = fmaf(a0, b2.w, acc[0][11]);
      acc[1][0] = fmaf(a1, b0.x, acc[1][0]);
      acc[1][1] = fmaf(a1, b0.y, acc[1][1]);
      acc[1][2] = fmaf(a1, b0.z, acc[1][2]);
      acc[1][3] = fmaf(a1, b0.w, acc[1][3]);
      acc[1][4] = fmaf(a1, b1.x, acc[1][4]);
      acc[1][5] = fmaf(a1, b1.y, acc[1][5]);
      acc[1][6] = fmaf(a1, b1.z, acc[1][6]);
      acc[1][7] = fmaf(a1, b1.w, acc[1][7]);
      acc[1][8] = fmaf(a1, b2.x, acc[1][8]);
      acc[1][9] = fmaf(a1, b2.y, acc[1][9]);
      acc[1][10] = fmaf(a1, b2.z, acc[1][10]);
      acc[1][11] = fmaf(a1, b2.w, acc[1][11]);
    }
  }
#pragma unroll
  for (int r = 0; r < 2; ++r) {
    float* p = part + ((size_t)ks * XP_M + m0 + ty * 2 + r) * 96 + tx * 12;
    *(float4*)(p + 0) = make_float4(acc[r][0], acc[r][1], acc[r][2], acc[r][3]);
    *(float4*)(p + 4) = make_float4(acc[r][4], acc[r][5], acc[r][6], acc[r][7]);
    *(float4*)(p + 8) = make_float4(acc[r][8], acc[r][9], acc[r][10], acc[r][11]);
  }
}

// ---------------------------------------------------------------------------
// Kernel 1b: reduce 8 K-slice partials -> xdb[m][96].
// ---------------------------------------------------------------------------
__global__ __launch_bounds__(256) void xreduce_kernel(
    const float* __restrict__ part, float* __restrict__ xdb) {
  const size_t gidx = (size_t)blockIdx.x * 256 + threadIdx.x;
  const float4* p4 = (const float4*)part;
  const size_t stride = (size_t)XP_M * 96 / 4;
  float4 s = p4[gidx];
#pragma unroll
  for (int ks = 1; ks < XP_KS; ++ks) {
    const float4 v = p4[(size_t)ks * stride + gidx];
    s.x += v.x; s.y += v.y; s.z += v.z; s.w += v.w;
  }
  ((float4*)xdb)[gidx] = s;
}

// ---------------------------------------------------------------------------
// Kernel 2: dt GEMM, both operands via LDS (round-8 version, works well).
// ---------------------------------------------------------------------------
__global__ __launch_bounds__(256) void dt_kernel(
    const float* __restrict__ xdb, const float* __restrict__ W_dt,
    const float* __restrict__ b_dt, float* __restrict__ dtb) {
  __shared__ float xst[64][68];
  __shared__ float wt[64][68];
  const int tid = threadIdx.x;
  const int tx = tid & 15;   // d-quad
  const int ty = tid >> 4;   // m-quad
  const int m0 = blockIdx.x * 64;
  const int d0 = blockIdx.y * 64;

  {
    const int qc = tid & 15, rr = tid >> 4;
#pragma unroll
    for (int j = 0; j < 4; ++j) {
      const int row = rr + j * 16;
      const float4 a = *(const float4*)(xdb + (size_t)(m0 + row) * 96 + qc * 4);
      xst[qc * 4 + 0][row] = a.x;
      xst[qc * 4 + 1][row] = a.y;
      xst[qc * 4 + 2][row] = a.z;
      xst[qc * 4 + 3][row] = a.w;
      const float4 w = *(const float4*)(W_dt + (size_t)(d0 + row) * R_ + qc * 4);
      wt[qc * 4 + 0][row] = w.x;
      wt[qc * 4 + 1][row] = w.y;
      wt[qc * 4 + 2][row] = w.z;
      wt[qc * 4 + 3][row] = w.w;
    }
  }
  __syncthreads();

  float acc[4][4];
#pragma unroll
  for (int i = 0; i < 4; ++i)
#pragma unroll
    for (int j = 0; j < 4; ++j) acc[i][j] = 0.f;

#pragma unroll
  for (int k = 0; k < 64; ++k) {
    const float4 bq = *(const float4*)(&wt[k][tx * 4]);
    const float4 aq = *(const float4*)(&xst[k][ty * 4]);
#pragma unroll
    for (int mi = 0; mi < 4; ++mi) {
      const float a = (mi == 0) ? aq.x : (mi == 1) ? aq.y : (mi == 2) ? aq.z : aq.w;
      acc[mi][0] = fmaf(a, bq.x, acc[mi][0]);
      acc[mi][1] = fmaf(a, bq.y, acc[mi][1]);
      acc[mi][2] = fmaf(a, bq.z, acc[mi][2]);
      acc[mi][3] = fmaf(a, bq.w, acc[mi][3]);
    }
  }

  const float4 bd = *(const float4*)(b_dt + d0 + tx * 4);
#pragma unroll
  for (int mi = 0; mi < 4; ++mi) {
    float4 o;
    float s;
    s = acc[mi][0] + bd.x;
    o.x = fmaxf(s, 0.f) + __logf(1.0f + __expf(-fabsf(s)));
    s = acc[mi][1] + bd.y;
    o.y = fmaxf(s, 0.f) + __logf(1.0f + __expf(-fabsf(s)));
    s = acc[mi][2] + bd.z;
    o.z = fmaxf(s, 0.f) + __logf(1.0f + __expf(-fabsf(s)));
    s = acc[mi][3] + bd.w;
    o.w = fmaxf(s, 0.f) + __logf(1.0f + __expf(-fabsf(s)));
    *(float4*)(dtb + (size_t)(m0 + ty * 4 + mi) * D_ + d0 + tx * 4) = o;
  }
}

// ---------------------------------------------------------------------------
// Kernel 3: LDS-staged chunked scan, 4 d per thread.
// Block: 256 = 16 dl x 16 n, thread owns d quad (d0+4dl .. d0+4dl+3) ->
// block spans 64 d. Per step: 1 ds_read_b64 (B,C) + 2 ds_read_b128
// (dt quad, dtx quad) feed 4 units (0.75 DS/unit, was 1.5) and give 4
// independent recurrence chains (ILP hides exp/fma latency with only
// 4 blocks/CU). Bank layout conflict-free (4-addr/16-bcast b128;
// 16-addr x 2-bank b64 covers 32 banks). Grid (B*16, CH8) = 1024 blocks,
// 20.25 KB LDS.
// ---------------------------------------------------------------------------
__global__ __launch_bounds__(256) void scan_kernel(
    const float* __restrict__ x, const float* __restrict__ xdb,
    const float* __restrict__ dtb, const float* __restrict__ A_log,
    float* __restrict__ summ, float* __restrict__ sumx) {
  __shared__ float dts[TB][64];
  __shared__ float dtx[TB][64];
  __shared__ float bcs[TB][34];  // pad 34: conflict-free scatter, b64-aligned
  const int tid = threadIdx.x;
  const int n = tid & 15;
  const int dl = tid >> 4;          // 0..15
  const int b = blockIdx.x >> 4;    // 0..7
  const int dtile = blockIdx.x & 15;
  const int c = blockIdx.y;         // 0..7
  const int d0 = dtile * 64;
  const int dbase = d0 + 4 * dl;

  float Av[4];
#pragma unroll
  for (int i = 0; i < 4; ++i)
    Av[i] = -__expf(A_log[(size_t)(dbase + i) * N_ + n]) * 1.44269504089f;

  const int t0 = c * TCH8;
  float cumP[4], loc[4], S1[4], S2[4];
#pragma unroll
  for (int i = 0; i < 4; ++i) {
    cumP[i] = 1.f; loc[i] = 0.f; S1[i] = 0.f; S2[i] = 0.f;
  }
  float xp0 = 0.f, xp1 = 0.f, xp2 = 0.f, xp3 = 0.f;  // xsum partials

  const int srow = tid >> 4, sc4 = (tid & 15) * 4;  // x/dt: 2 rows each
  const int brow = tid >> 3, bc4 = (tid & 7) * 4;   // bc tile: 1 each
  const int bpos = ((bc4 * 2) & 31) + (bc4 >> 4);

  for (int tb = 0; tb < TCH8; tb += TB) {
    const int tbase = t0 + tb;
    __syncthreads();
    {
#pragma unroll
      for (int j = 0; j < 2; ++j) {
        const int row = srow + j * 16;
        const size_t g = ((size_t)b * L_ + tbase + row) * D_ + d0 + sc4;
        const float4 xv = *(const float4*)(x + g);
        const float4 dv = *(const float4*)(dtb + g);
        *(float4*)(&dts[row][sc4]) = dv;
        *(float4*)(&dtx[row][sc4]) =
            make_float4(xv.x * dv.x, xv.y * dv.y, xv.z * dv.z, xv.w * dv.w);
        xp0 += xv.x; xp1 += xv.y; xp2 += xv.z; xp3 += xv.w;
      }
      const size_t gb = ((size_t)b * L_ + tbase + brow) * 96 + 64 + bc4;
      const float4 bc = *(const float4*)(xdb + gb);
      bcs[brow][bpos + 0] = bc.x;
      bcs[brow][bpos + 2] = bc.y;
      bcs[brow][bpos + 4] = bc.z;
      bcs[brow][bpos + 6] = bc.w;
    }
    __syncthreads();
#pragma unroll
    for (int tt = 0; tt < TB; ++tt) {
      const float2 bv = *(const float2*)(&bcs[tt][2 * n]);   // (B[n], C[n])
      const float4 dv = *(const float4*)(&dts[tt][4 * dl]);
      const float4 px = *(const float4*)(&dtx[tt][4 * dl]);
      const float dvv[4] = {dv.x, dv.y, dv.z, dv.w};
      const float pxv[4] = {px.x, px.y, px.z, px.w};
#pragma unroll
      for (int i = 0; i < 4; ++i) {
        const float e = exp2_fast(dvv[i] * Av[i]);
        cumP[i] *= e;
        loc[i] = fmaf(e, loc[i], pxv[i] * bv.x);
        S1[i] = fmaf(cumP[i], bv.y, S1[i]);
        S2[i] = fmaf(loc[i], bv.y, S2[i]);
      }
    }
  }
#pragma unroll
  for (int i = 0; i < 4; ++i) {
    const size_t si = (((size_t)c * B_ + b) * D_ + dbase + i) * N_ + n;
    ((float4*)summ)[si] = make_float4(cumP[i], S1[i], S2[i], loc[i]);
  }

  // xsum: thread's partials cover cols sc4..sc4+3 (rows srow, srow+16 of
  // each staging pass). Reduce the 16 row-threads per column via LDS.
  __syncthreads();
  *(float4*)(&dtx[srow][sc4]) = make_float4(xp0, xp1, xp2, xp3);
  __syncthreads();
  if (tid < 64) {
    float s = 0.f;
#pragma unroll
    for (int r = 0; r < 16; ++r) s += dtx[r][tid];
    sumx[((size_t)c * B_ + b) * D_ + d0 + tid] = s;
  }
}

// ---------------------------------------------------------------------------
// Kernel 3b: exact sequential chunk combine + n-reduce -> pooled.
// ---------------------------------------------------------------------------
__global__ __launch_bounds__(256) void combine_kernel(
    const float* __restrict__ summ, const float* __restrict__ sumx,
    const float* __restrict__ D_param, float* __restrict__ pooled) {
  const int gid = blockIdx.x * 256 + threadIdx.x;  // 0..131071
  const int n = gid & 15;
  const int d = (gid >> 4) & (D_ - 1);
  const int b = gid >> 14;  // 0..7
  float hin = 0.f, acc = 0.f;
  const float4* s4 = (const float4*)summ;
#pragma unroll
  for (int c = 0; c < CH8; ++c) {
    const float4 f = s4[(((size_t)c * B_ + b) * D_ + d) * N_ + n];
    acc = fmaf(hin, f.y, acc) + f.z;
    hin = fmaf(f.x, hin, f.w);
  }
  acc += __shfl_xor(acc, 1);
  acc += __shfl_xor(acc, 2);
  acc += __shfl_xor(acc, 4);
  acc += __shfl_xor(acc, 8);
  if (n == 0) {
    float xst = 0.f;
#pragma unroll
    for (int c = 0; c < CH8; ++c)
      xst += sumx[((size_t)c * B_ + b) * D_ + d];
    pooled[(size_t)b * D_ + d] =
        (acc + D_param[d] * xst) * (1.0f / (float)L_);
  }
}

// ---------------------------------------------------------------------------
// Kernel 4: logits. One wave per class; all 8 batches from LDS-staged pooled.
// ---------------------------------------------------------------------------
__global__ __launch_bounds__(256) void cls_kernel(
    const float* __restrict__ pooled, const float* __restrict__ W_cls,
    const float* __restrict__ b_cls, float* __restrict__ out) {
  __shared__ float pool[B_ * D_];  // 32 KB
  const int tid = threadIdx.x;
  const int c = blockIdx.x * 4 + (tid >> 6);
  const int lane = tid & 63;

#pragma unroll
  for (int j = 0; j < 8; ++j) {
    const int f4 = tid + j * 256;
    ((float4*)pool)[f4] = ((const float4*)pooled)[f4];
  }
  __syncthreads();

  float accb[B_];
#pragma unroll
  for (int b = 0; b < B_; ++b) accb[b] = 0.f;

#pragma unroll
  for (int i = 0; i < 4; ++i) {
    const float4 wv =
        *(const float4*)(W_cls + (size_t)c * D_ + i * 256 + lane * 4);
#pragma unroll
    for (int b = 0; b < B_; ++b) {
      const float4 p = *(const float4*)(&pool[b * D_ + i * 256 + lane * 4]);
      accb[b] = fmaf(wv.x, p.x,
                fmaf(wv.y, p.y, fmaf(wv.z, p.z, fmaf(wv.w, p.w, accb[b]))));
    }
  }
#pragma unroll
  for (int off = 1; off < 64; off <<= 1) {
#pragma unroll
    for (int b = 0; b < B_; ++b) accb[b] += __shfl_xor(accb[b], off);
  }
  if (lane < B_) out[(size_t)lane * NC_ + c] = accb[lane] + b_cls[c];
}

// ---------------------------------------------------------------------------
extern "C" void kernel_launch(void* const* d_in, const int* in_sizes, int n_in,
                              void* d_out, int out_size, void* d_ws,
                              size_t ws_size, hipStream_t stream) {
  const float* x = (const float*)d_in[0];
  const float* A_log = (const float*)d_in[1];
  const float* D_param = (const float*)d_in[2];
  const float* W_xproj = (const float*)d_in[3];
  const float* W_dt = (const float*)d_in[4];
  const float* b_dt = (const float*)d_in[5];
  const float* W_cls = (const float*)d_in[6];
  const float* b_cls = (const float*)d_in[7];
  float* out = (float*)d_out;

  // ws layout, flat, no aliasing (~79 MB of ~268 MB available):
  float* ws_f = (float*)d_ws;
  float* xdb = ws_f;                               // 786,432 f
  float* part = xdb + (size_t)XP_M * 96;           // 6,291,456 f
  float* dtb = part + (size_t)XP_KS * XP_M * 96;   // 8,388,608 f
  float* summ = dtb + (size_t)XP_M * D_;           // 4,194,304 f
  float* sumx = summ + (size_t)CH8 * B_ * D_ * N_ * 4;  // 65,536 f
  float* pooled = sumx + (size_t)CH8 * B_ * D_;    // 8,192 f

  xproj_kernel<<<dim3(XP_M / XP_TM, XP_KS), dim3(256), 0, stream>>>(
      x, W_xproj, part);
  xreduce_kernel<<<dim3(XP_M * 96 / 4 / 256), dim3(256), 0, stream>>>(part,
                                                                      xdb);
  dt_kernel<<<dim3(XP_M / 64, D_ / 64), dim3(256), 0, stream>>>(xdb, W_dt,
                                                                b_dt, dtb);
  scan_kernel<<<dim3(B_ * 16, CH8), dim3(256), 0, stream>>>(x, xdb, dtb,
                                                            A_log, summ, sumx);
  combine_kernel<<<dim3(B_ * D_ * N_ / 256), dim3(256), 0, stream>>>(
      summ, sumx, D_param, pooled);
  cls_kernel<<<dim3(NC_ / 4), dim3(256), 0, stream>>>(pooled, W_cls, b_cls,
                                                      out);
}